// Round 18
// baseline (418.821 us; speedup 1.0000x reference)
//
#include <hip/hip_runtime.h>
#include <hip/hip_cooperative_groups.h>

// ---------- helpers ----------
__device__ __forceinline__ float bf2f(unsigned short u) {
  union { unsigned int i; float f; } v; v.i = ((unsigned int)u) << 16; return v.f;
}
__device__ __forceinline__ unsigned short f2bf(float f) {
  union { float f; unsigned int i; } v; v.f = f;
  unsigned int x = v.i;
  return (unsigned short)((x + 0x7fffu + ((x >> 16) & 1u)) >> 16);
}
__device__ __forceinline__ float sigmf(float x) { return 1.f / (1.f + __expf(-x)); }
__device__ __forceinline__ float tanhfast(float x) {
  float xc = fminf(fmaxf(x, -15.f), 15.f);
  float e = __expf(2.f * xc);
  return (e - 1.f) / (e + 1.f);
}

typedef float f32x4 __attribute__((ext_vector_type(4)));
typedef short short8v __attribute__((ext_vector_type(8)));
typedef short short4v __attribute__((ext_vector_type(4)));

// pack 8 f32 -> 8 bf16 (truncate)
__device__ __forceinline__ short8v pack8(const float* p) {
  union { short8v s; unsigned int u[4]; } r;
#pragma unroll
  for (int i = 0; i < 4; ++i) {
    unsigned int lo = __float_as_uint(p[2 * i]) >> 16;
    unsigned int hi = __float_as_uint(p[2 * i + 1]) & 0xFFFF0000u;
    r.u[i] = hi | lo;
  }
  return r.s;
}

#define KP 1984
#define GRU_BLOCKS 245
#define C1_PLANE 2860

// ---------- fused prep: cvt w_hh [0,2048) | w1frag | w2frag | featpad ----------
__global__ void k_prep(const float* __restrict__ w_hh, unsigned short* __restrict__ whh_bf,
                       const float* __restrict__ w1, const float* __restrict__ b1,
                       unsigned short* __restrict__ w1f,
                       const float* __restrict__ w2, unsigned short* __restrict__ w2f,
                       unsigned short* __restrict__ feat_bf,
                       unsigned long long* __restrict__ hb0,
                       unsigned long long* __restrict__ hb1) {
  const int b = blockIdx.x;
  const int tid = threadIdx.x;
  if (b < 2048) {
    const int n4 = 5880 * 1960 / 4;
    for (int i = b * 256 + tid; i < n4; i += 2048 * 256) {
      float4 v = *reinterpret_cast<const float4*>(&w_hh[i * 4]);
      ushort4 u;
      u.x = f2bf(v.x); u.y = f2bf(v.y); u.z = f2bf(v.z); u.w = f2bf(v.w);
      *reinterpret_cast<ushort4*>(&whh_bf[i * 4]) = u;
    }
  } else if (b < 2072) {
    int idx = (b - 2048) * 256 + tid;
    if (idx < 4 * 3 * 64 * 8) {
      int j = idx & 7, l = (idx >> 3) & 63;
      int rest = idx >> 9;
      int s = rest % 3, ocf = rest / 3;
      int oc = ocf * 16 + (l & 15);
      int k = s * 32 + (l >> 4) * 8 + j;
      float v = 0.f;
      if (k < 64)       v = w1[oc * 81 + (k >> 3) * 9 + (k & 7)];
      else if (k < 72)  v = w1[oc * 81 + 72 + (k - 64)];
      else if (k < 80)  v = w1[oc * 81 + (k - 72) * 9 + 8];
      else if (k == 80) v = w1[oc * 81 + 80];
      else if (k == 81) v = b1[oc];
      w1f[idx] = f2bf(v);
    }
  } else if (b < 2136) {
    int idx = (b - 2072) * 256 + tid;
    if (idx < 32 * 64 * 8) {
      int j = idx & 7, l = (idx >> 3) & 63, s = idx >> 9;
      int oc = l & 15;
      int k = s * 32 + (l >> 4) * 8 + j;
      int t = k >> 6, ch = k & 63, fr = t >> 2, fc = t & 3;
      float v = (oc < 5) ? w2[((oc * 64 + ch) * 4 + fr) * 4 + fc] : 0.f;
      w2f[idx] = f2bf(v);
    }
  } else {
    for (int i = tid; i < 128 * 24; i += 256) {
      int n = i / 24, k = 1960 + i % 24;
      feat_bf[(size_t)n * KP + k] = 0;
    }
    for (int i = tid; i < 3920; i += 256) {
      hb0[i] = 0ull;
      hb1[i] = 0ull;
    }
  }
}

// ---------- kernel 1: conv1 MFMA + pool + sigmoid (proven; conflict-free plane stride) ----------
__global__ __launch_bounds__(256) void k_conv1(const float* __restrict__ x,
                                               const unsigned short* __restrict__ w1f,
                                               unsigned short* __restrict__ pool1) {
  const int n = blockIdx.x, qrg = blockIdx.y;
  const int b = n >> 5, w = n & 31;
  __shared__ __align__(16) unsigned short s_b[4 * C1_PLANE];  // 22880 B
  const int tid = threadIdx.x;
  for (int i = tid; i < 20 * 132; i += 256) {
    int lr = i / 132, lc = i % 132;
    int f = 12 * qrg + lr - 2;
    int t = lc - 2;
    float v = 0.f;
    if (f >= 0 && f < 257 && t >= 0 && t < 128)
      v = x[((size_t)b * 258 + 1 + f) * 2176 + w * 64 + t];
    unsigned short bf = f2bf(v);
#pragma unroll
    for (int m = 0; m < 4; ++m) s_b[m * C1_PLANE + lr * 140 + lc + m] = bf;
  }
  const int lane = tid & 63, wv = tid >> 6;
  short8v bw[4][3];
#pragma unroll
  for (int ocf = 0; ocf < 4; ++ocf)
#pragma unroll
    for (int s = 0; s < 3; ++s)
      bw[ocf][s] = *reinterpret_cast<const short8v*>(&w1f[(((ocf * 3) + s) * 64 + lane) * 8]);
  __syncthreads();

  const int qr = qrg * 4 + wv;
  const int li = lane & 15, g = lane >> 4;

  for (int pgt = 0; pgt < 3; ++pgt) {
    int pg = pgt * 16 + li;
    if (pg > 40) pg = 40;
    f32x4 pm[4];
#pragma unroll
    for (int ocf = 0; ocf < 4; ++ocf) pm[ocf] = (f32x4){-3.4e38f, -3.4e38f, -3.4e38f, -3.4e38f};

    for (int rr = 0; rr < 3; ++rr) {
      const int lrb = 3 * wv + rr;
#pragma unroll
      for (int phi = 0; phi < 3; ++phi) {
        const int c = 3 * pg + phi;
        const int m = (-c) & 3;
        const unsigned short* hb = &s_b[m * C1_PLANE + c + m];
        f32x4 acc[4];
#pragma unroll
        for (int ocf = 0; ocf < 4; ++ocf) acc[ocf] = (f32x4){0.f, 0.f, 0.f, 0.f};
        const unsigned short* p0 = hb + (lrb + g) * 140;
        short8v a0 = __builtin_shufflevector(*reinterpret_cast<const short4v*>(p0),
                                             *reinterpret_cast<const short4v*>(p0 + 4),
                                             0, 1, 2, 3, 4, 5, 6, 7);
#pragma unroll
        for (int ocf = 0; ocf < 4; ++ocf)
          acc[ocf] = __builtin_amdgcn_mfma_f32_16x16x32_bf16(a0, bw[ocf][0], acc[ocf], 0, 0, 0);
        const unsigned short* p1 = p0 + 4 * 140;
        short8v a1 = __builtin_shufflevector(*reinterpret_cast<const short4v*>(p1),
                                             *reinterpret_cast<const short4v*>(p1 + 4),
                                             0, 1, 2, 3, 4, 5, 6, 7);
#pragma unroll
        for (int ocf = 0; ocf < 4; ++ocf)
          acc[ocf] = __builtin_amdgcn_mfma_f32_16x16x32_bf16(a1, bw[ocf][1], acc[ocf], 0, 0, 0);
        short8v a2;
        if (g == 0) {
          const unsigned short* p2 = p0 + 8 * 140;
          a2 = __builtin_shufflevector(*reinterpret_cast<const short4v*>(p2),
                                       *reinterpret_cast<const short4v*>(p2 + 4),
                                       0, 1, 2, 3, 4, 5, 6, 7);
        } else if (g == 1) {
          const unsigned short* pv = &s_b[lrb * 140 + c + 8];
          union { short8v s8; unsigned int u[4]; } r;
          r.u[0] = (unsigned)pv[0]       | ((unsigned)pv[140] << 16);
          r.u[1] = (unsigned)pv[2 * 140] | ((unsigned)pv[3 * 140] << 16);
          r.u[2] = (unsigned)pv[4 * 140] | ((unsigned)pv[5 * 140] << 16);
          r.u[3] = (unsigned)pv[6 * 140] | ((unsigned)pv[7 * 140] << 16);
          a2 = r.s8;
        } else if (g == 2) {
          union { short8v s8; unsigned int u[4]; } r;
          r.u[0] = (unsigned)s_b[(lrb + 8) * 140 + c + 8] | 0x3F800000u;  // corner | bf16(1.0)<<16
          r.u[1] = 0; r.u[2] = 0; r.u[3] = 0;
          a2 = r.s8;
        } else {
          a2 = (short8v){0, 0, 0, 0, 0, 0, 0, 0};
        }
#pragma unroll
        for (int ocf = 0; ocf < 4; ++ocf)
          acc[ocf] = __builtin_amdgcn_mfma_f32_16x16x32_bf16(a2, bw[ocf][2], acc[ocf], 0, 0, 0);
#pragma unroll
        for (int ocf = 0; ocf < 4; ++ocf) {
#pragma unroll
          for (int i = 0; i < 4; ++i) pm[ocf][i] = fmaxf(pm[ocf][i], acc[ocf][i]);
        }
      }
    }
#pragma unroll
    for (int ocf = 0; ocf < 4; ++ocf) {
#pragma unroll
      for (int i = 0; i < 4; ++i) {
        int pg2 = pgt * 16 + g * 4 + i;
        if (pg2 <= 40) {
          int oc = ocf * 16 + li;
          pool1[(((size_t)n * 84 + qr) * 41 + pg2) * 64 + oc] = f2bf(sigmf(pm[ocf][i]));
        }
      }
    }
  }
}

// ---------- kernel 2: conv2 MFMA, LDS-staged A, weights in regs ----------
__global__ __launch_bounds__(128, 2) void k_conv2(const unsigned short* __restrict__ pool1,
                                                  const unsigned short* __restrict__ w2f,
                                                  const float* __restrict__ b2,
                                                  unsigned short* __restrict__ feat_bf) {
  const int n = blockIdx.x, qg = blockIdx.y;
  __shared__ __align__(16) unsigned short s_a[9 * 46 * 64];
  const int tid = threadIdx.x;
  const int lane = tid & 63, wv = tid >> 6;
  short8v bwr[32];
#pragma unroll
  for (int s = 0; s < 32; ++s)
    bwr[s] = *reinterpret_cast<const short8v*>(&w2f[(s * 64 + lane) * 8]);
  const int r0 = 6 * qg - 2;
  for (int idx = tid; idx < 9 * 46 * 8; idx += 128) {
    int row = idx / (46 * 8);
    int rem = idx - row * (46 * 8);
    int lc = rem >> 3, cp = rem & 7;
    int gr = r0 + row, gc = lc - 2;
    short8v v = {0, 0, 0, 0, 0, 0, 0, 0};
    if ((unsigned)gr < 84u && (unsigned)gc < 41u)
      v = *reinterpret_cast<const short8v*>(&pool1[(((size_t)n * 84 + gr) * 41 + gc) * 64 + cp * 8]);
    int rot = (cp * 8 + lc * 8) & 63;
    *reinterpret_cast<short8v*>(&s_a[(row * 46 + lc) * 64 + rot]) = v;
  }
  __syncthreads();

  const int q = qg * 2 + wv;
  const int li = lane & 15, g = lane >> 4;
  const int pg = li > 13 ? 13 : li;
  f32x4 pm = (f32x4){-3.4e38f, -3.4e38f, -3.4e38f, -3.4e38f};

  for (int rr = 0; rr < 3; ++rr) {
#pragma unroll
    for (int phi = 0; phi < 3; ++phi) {
      f32x4 acc[4];
#pragma unroll
      for (int i = 0; i < 4; ++i) acc[i] = (f32x4){0.f, 0.f, 0.f, 0.f};
#pragma unroll
      for (int s = 0; s < 32; ++s) {
        const int t = s >> 1, h = s & 1;
        const int fr = t >> 2, fc = t & 3;
        const int srow = 3 * wv + rr + fr;
        const int lc = 3 * pg + phi + fc;
        const int rot = (h * 32 + g * 8 + lc * 8) & 63;
        short8v a = *reinterpret_cast<const short8v*>(&s_a[(srow * 46 + lc) * 64 + rot]);
        acc[s & 3] = __builtin_amdgcn_mfma_f32_16x16x32_bf16(a, bwr[s], acc[s & 3], 0, 0, 0);
      }
      f32x4 sum;
#pragma unroll
      for (int i = 0; i < 4; ++i) sum[i] = (acc[0][i] + acc[1][i]) + (acc[2][i] + acc[3][i]);
#pragma unroll
      for (int i = 0; i < 4; ++i) pm[i] = fmaxf(pm[i], sum[i]);
    }
  }
  if (li < 5) {
#pragma unroll
    for (int i = 0; i < 4; ++i) {
      int pq = g * 4 + i;
      if (pq < 14)
        feat_bf[(size_t)n * KP + li * 392 + q * 14 + pq] = f2bf(sigmf(pm[i] + b2[li]));
    }
  }
}

// ---------- kernel 4: gi MFMA GEMM (reads w_ih f32 directly, inline bf16 pack) ----------
__global__ __launch_bounds__(256) void k_gi(const unsigned short* __restrict__ feat_bf,
                                            const float* __restrict__ w_ih,
                                            const float* __restrict__ b_ih,
                                            float* __restrict__ gi) {
  const int bx = blockIdx.x, bm = blockIdx.y;
  const int w = threadIdx.x >> 6, lane = threadIdx.x & 63;
  const int li = lane & 15, g = lane >> 4;
  const int j = bx * 16 + li;
  const int jc = j < 5880 ? j : 5879;
  const unsigned short* ap = feat_bf + (size_t)(bm * 64 + w * 16 + li) * KP + g * 8;
  const float* bp = w_ih + (size_t)jc * 1960 + g * 8;
  const short8v z8 = {0, 0, 0, 0, 0, 0, 0, 0};
  f32x4 acc0 = (f32x4){0.f, 0.f, 0.f, 0.f};
  f32x4 acc1 = (f32x4){0.f, 0.f, 0.f, 0.f};
  for (int kc = 0; kc < 62; kc += 2) {
    short8v a0 = *reinterpret_cast<const short8v*>(ap + kc * 32);
    short8v a1 = *reinterpret_cast<const short8v*>(ap + kc * 32 + 32);
    short8v b0 = pack8(bp + kc * 32);
    short8v b1 = (kc != 60 || g == 0) ? pack8(bp + kc * 32 + 32) : z8;
    acc0 = __builtin_amdgcn_mfma_f32_16x16x32_bf16(a0, b0, acc0, 0, 0, 0);
    acc1 = __builtin_amdgcn_mfma_f32_16x16x32_bf16(a1, b1, acc1, 0, 0, 0);
  }
  if (j < 5880) {
    const float bi = b_ih[j];
    const int n0 = bm * 64 + w * 16 + g * 4;
#pragma unroll
    for (int i = 0; i < 4; ++i)
      gi[(size_t)(n0 + i) * 5880 + j] = acc0[i] + acc1[i] + bi;
  }
}

// ---------- kernel 5: persistent GRU (bf16 preload, 2 barriers/step, fused fc) ----------
__global__ __launch_bounds__(512) void k_gru(const unsigned short* __restrict__ whh,
                                             const float* __restrict__ b_hh,
                                             const float* __restrict__ gi,
                                             const float* __restrict__ hx0,
                                             unsigned long long* __restrict__ hb0,
                                             unsigned long long* __restrict__ hb1,
                                             const float* __restrict__ fc_w,
                                             const float* __restrict__ fc_b,
                                             const int* __restrict__ labels,
                                             float* __restrict__ out) {
  __shared__ __align__(16) unsigned short s_w[2 * 62 * 64 * 8];  // 126976 B
  __shared__ __align__(16) unsigned short s_h[4 * 1984];         // 15872 B
  __shared__ float s_part[4 * 2 * 64 * 4];                        // 8192 B
  __shared__ float s_gi[2][96];
  const int tid = threadIdx.x;
  const int bid = blockIdx.x;
  const int k0 = bid * 8;
  const int lane = tid & 63, wv = tid >> 6;
  const int li = lane & 15, g2 = lane >> 4;

  // preload w A-fragments from bf16 global (consecutive threads -> consecutive LDS 16B)
  for (int idx = tid; idx < 2 * 62 * 64; idx += 512) {
    int mt = idx / 3968;
    int rem = idx - mt * 3968;
    int kc = rem >> 6, l = rem & 63;
    int lli = l & 15, lg2 = l >> 4;
    int k = kc * 32 + lg2 * 8;
    short8v v = {0, 0, 0, 0, 0, 0, 0, 0};
    bool rowok = (mt == 0) ? true : (lli < 8);
    if (rowok && k < 1960) {
      int g = (mt == 0) ? (lli >> 3) : 2;
      int kk = (mt == 0) ? (lli & 7) : lli;
      v = *reinterpret_cast<const short8v*>(&whh[(size_t)(g * 1960 + k0 + kk) * 1960 + k]);
    }
    *reinterpret_cast<short8v*>(&s_w[(size_t)idx * 8]) = v;
  }
  for (int i = tid; i < 4 * 992; i += 512) reinterpret_cast<unsigned int*>(s_h)[i] = 0u;

  float hp0 = 0.f, hp1 = 0.f, bhr0 = 0, bhr1 = 0, bhz0 = 0, bhz1 = 0, bhn0 = 0, bhn1 = 0;
  if (tid < 16) {
    int cb = tid >> 2, p = tid & 3;
    int k = k0 + 2 * p;
    hp0 = hx0[cb * 1960 + k];
    hp1 = hx0[cb * 1960 + k + 1];
    bhr0 = b_hh[k];         bhr1 = b_hh[k + 1];
    bhz0 = b_hh[1960 + k];  bhz1 = b_hh[1960 + k + 1];
    bhn0 = b_hh[3920 + k];  bhn1 = b_hh[3920 + k + 1];
  }
  __syncthreads();

  for (int t = 0; t < 32; ++t) {
    // ---- stage h (batched tagged poll for t>=1) + gi prefetch (double-buffered) ----
    if (t == 0) {
      for (int i = tid; i < 7840; i += 512) {
        int b = i / 1960, k = i - b * 1960;
        s_h[b * 1984 + k] = f2bf(hx0[i]);
      }
    } else {
      const unsigned long long* hin = (t & 1) ? hb1 : hb0;
      unsigned pend = 0;
#pragma unroll
      for (int r = 0; r < 8; ++r)
        if (tid + (r << 9) < 3920) pend |= (1u << r);
      while (pend) {
        unsigned long long v[8];
#pragma unroll
        for (int r = 0; r < 8; ++r)
          if (pend & (1u << r))
            v[r] = __hip_atomic_load(&hin[tid + (r << 9)], __ATOMIC_RELAXED,
                                     __HIP_MEMORY_SCOPE_AGENT);
#pragma unroll
        for (int r = 0; r < 8; ++r) {
          if ((pend & (1u << r)) && (unsigned)(v[r] >> 32) >= (unsigned)t) {
            int i = tid + (r << 9);
            int b = i / 980, kp = i - b * 980;
            reinterpret_cast<unsigned int*>(s_h)[b * 992 + kp] = (unsigned)v[r];
            pend &= ~(1u << r);
          }
        }
        if (pend) __builtin_amdgcn_s_sleep(0);
      }
    }
    if (tid < 96) {
      int gg = tid >> 5, bb = (tid >> 3) & 3, kk = tid & 7;
      s_gi[t & 1][tid] = gi[(size_t)(bb * 32 + t) * 5880 + gg * 1960 + k0 + kk];
    }
    __syncthreads();  // barrier A: stage complete

    // ---- MFMA dot (waves 0-3) ----
    if (wv < 4) {
      f32x4 acc0 = (f32x4){0.f, 0.f, 0.f, 0.f};
      f32x4 acc1 = (f32x4){0.f, 0.f, 0.f, 0.f};
      for (int kc = wv; kc < 62; kc += 4) {
        short8v bfr = *reinterpret_cast<const short8v*>(&s_h[(li & 3) * 1984 + kc * 32 + g2 * 8]);
        short8v a0 = *reinterpret_cast<const short8v*>(&s_w[((size_t)kc * 64 + lane) * 8]);
        short8v a1 = *reinterpret_cast<const short8v*>(&s_w[((size_t)(62 + kc) * 64 + lane) * 8]);
        acc0 = __builtin_amdgcn_mfma_f32_16x16x32_bf16(a0, bfr, acc0, 0, 0, 0);
        acc1 = __builtin_amdgcn_mfma_f32_16x16x32_bf16(a1, bfr, acc1, 0, 0, 0);
      }
      *reinterpret_cast<f32x4*>(&s_part[((wv * 2 + 0) * 64 + lane) * 4]) = acc0;
      *reinterpret_cast<f32x4*>(&s_part[((wv * 2 + 1) * 64 + lane) * 4]) = acc1;
    }
    __syncthreads();  // barrier B: s_part ready

    // ---- update (16 threads) + publish; other waves fall through to next stage ----
    unsigned long long* hout = (t & 1) ? hb0 : hb1;
    if (tid < 16) {
      const int cb = tid >> 2, p = tid & 3;
      const int kk = 2 * p;
      auto psum = [&](int mt, int m) -> float {
        int base = mt * 256 + ((m >> 2) * 16 + cb) * 4 + (m & 3);
        return ((s_part[base] + s_part[base + 512]) +
                (s_part[base + 1024] + s_part[base + 1536]));
      };
      float ghr0 = psum(0, kk),     ghr1 = psum(0, kk + 1);
      float ghz0 = psum(0, 8 + kk), ghz1 = psum(0, 8 + kk + 1);
      float ghn0 = psum(1, kk),     ghn1 = psum(1, kk + 1);
      float r0 = sigmf(s_gi[t & 1][cb * 8 + kk] + ghr0 + bhr0);
      float z0 = sigmf(s_gi[t & 1][32 + cb * 8 + kk] + ghz0 + bhz0);
      float n0 = tanhfast(s_gi[t & 1][64 + cb * 8 + kk] + r0 * (ghn0 + bhn0));
      float h0v = (1.f - z0) * n0 + z0 * hp0;
      float r1 = sigmf(s_gi[t & 1][cb * 8 + kk + 1] + ghr1 + bhr1);
      float z1 = sigmf(s_gi[t & 1][32 + cb * 8 + kk + 1] + ghz1 + bhz1);
      float n1 = tanhfast(s_gi[t & 1][64 + cb * 8 + kk + 1] + r1 * (ghn1 + bhn1));
      float h1v = (1.f - z1) * n1 + z1 * hp1;
      hp0 = h0v; hp1 = h1v;
      unsigned long long packed =
          ((unsigned long long)(unsigned)(t + 1) << 32) |
          (unsigned long long)((unsigned)f2bf(h0v) | ((unsigned)f2bf(h1v) << 16));
      __hip_atomic_store(&hout[cb * 980 + (k0 >> 1) + p], packed,
                         __ATOMIC_RELAXED, __HIP_MEMORY_SCOPE_AGENT);
    }
    // no loop-end barrier: next stage writes s_h (dot done at barrier B) and
    // s_gi[(t+1)&1] (update reads s_gi[t&1]); dot(next) gated by barrier A.
  }

  // ---- fused fc + softmax (block 0 only) ----
  if (bid == 0) {
    unsigned pend = 0;
#pragma unroll
    for (int r = 0; r < 8; ++r)
      if (tid + (r << 9) < 3920) pend |= (1u << r);
    while (pend) {
      unsigned long long v[8];
#pragma unroll
      for (int r = 0; r < 8; ++r)
        if (pend & (1u << r))
          v[r] = __hip_atomic_load(&hb0[tid + (r << 9)], __ATOMIC_RELAXED,
                                   __HIP_MEMORY_SCOPE_AGENT);
#pragma unroll
      for (int r = 0; r < 8; ++r) {
        if ((pend & (1u << r)) && (unsigned)(v[r] >> 32) >= 32u) {
          int i = tid + (r << 9);
          int b = i / 980, kp = i - b * 980;
          reinterpret_cast<unsigned int*>(s_h)[b * 992 + kp] = (unsigned)v[r];
          pend &= ~(1u << r);
        }
      }
      if (pend) __builtin_amdgcn_s_sleep(0);
    }
    __syncthreads();
    if (tid < 64) {
      const int l = tid;
      float acc[8];
#pragma unroll
      for (int i = 0; i < 8; ++i) acc[i] = 0.f;
      for (int k = l; k < 1960; k += 64) {
        const float w0 = fc_w[k], w1 = fc_w[1960 + k];
#pragma unroll
        for (int b = 0; b < 4; ++b) {
          const float hv = bf2f(s_h[b * 1984 + k]);
          acc[b * 2 + 0] += hv * w0;
          acc[b * 2 + 1] += hv * w1;
        }
      }
#pragma unroll
      for (int i = 0; i < 8; ++i) {
        float a = acc[i];
#pragma unroll
        for (int off = 32; off; off >>= 1) a += __shfl_xor(a, off, 64);
        acc[i] = a;
      }
      if (l == 0) {
#pragma unroll
        for (int b = 0; b < 4; ++b) {
          const float l0 = acc[b * 2] + fc_b[0], l1 = acc[b * 2 + 1] + fc_b[1];
          const float m = fmaxf(l0, l1);
          const float e0 = __expf(l0 - m), e1 = __expf(l1 - m);
          const float s = e0 + e1;
          out[b * 2 + 0] = e0 / s;
          out[b * 2 + 1] = e1 / s;
        }
        for (int i = 0; i < 4; ++i) out[8 + i] = (float)labels[i];
      }
    }
  }
}

extern "C" void kernel_launch(void* const* d_in, const int* in_sizes, int n_in,
                              void* d_out, int out_size, void* d_ws, size_t ws_size,
                              hipStream_t stream) {
  const float* x       = (const float*)d_in[0];
  const float* hx0     = (const float*)d_in[1];
  const int*   labels  = (const int*)d_in[2];
  const float* conv1_w = (const float*)d_in[3];
  const float* conv1_b = (const float*)d_in[4];
  const float* conv2_w = (const float*)d_in[5];
  const float* conv2_b = (const float*)d_in[6];
  const float* w_ih    = (const float*)d_in[7];
  const float* w_hh    = (const float*)d_in[8];
  const float* b_ih    = (const float*)d_in[9];
  const float* b_hh    = (const float*)d_in[10];
  const float* fc_w    = (const float*)d_in[11];
  const float* fc_b    = (const float*)d_in[12];

  char* ws = (char*)d_ws;
  size_t off = 0;
  unsigned short* pool1 = (unsigned short*)(ws + off); off += (size_t)128 * 84 * 41 * 64 * 2;  // 56.4MB
  unsigned short* feat_bf = (unsigned short*)(ws + off); off += (size_t)128 * KP * 2;          // 0.5MB
  float* gi    = (float*)(ws + off); off += (size_t)128 * 5880 * 4;                            // 3.0MB
  unsigned short* whh_bf = (unsigned short*)(ws + off); off += (size_t)5880 * 1960 * 2;        // 23.0MB
  unsigned long long* hb0 = (unsigned long long*)(ws + off); off += (size_t)4 * 980 * 8;       // 31.4KB
  unsigned long long* hb1 = (unsigned long long*)(ws + off); off += (size_t)4 * 980 * 8;       // 31.4KB
  unsigned short* w1f = (unsigned short*)(ws + off); off += (size_t)4 * 3 * 64 * 8 * 2;        // 12KB
  unsigned short* w2f = (unsigned short*)(ws + off); off += (size_t)32 * 64 * 8 * 2;           // 32KB

  k_prep<<<2137, 256, 0, stream>>>(w_hh, whh_bf, conv1_w, conv1_b, w1f,
                                   conv2_w, w2f, feat_bf, hb0, hb1);

  dim3 g1(128, 21);
  k_conv1<<<g1, 256, 0, stream>>>(x, w1f, pool1);

  dim3 g2(128, 14);
  k_conv2<<<g2, 128, 0, stream>>>(pool1, w2f, conv2_b, feat_bf);

  dim3 g3(368, 2);
  k_gi<<<g3, 256, 0, stream>>>(feat_bf, w_ih, b_ih, gi);

  // all 32 GRU steps + fused fc; final h_32 in hb0; out written by block 0
  void* gru_args[] = {(void*)&whh_bf, (void*)&b_hh, (void*)&gi, (void*)&hx0,
                      (void*)&hb0, (void*)&hb1, (void*)&fc_w, (void*)&fc_b,
                      (void*)&labels, (void*)&d_out};
  hipLaunchCooperativeKernel((const void*)k_gru, dim3(GRU_BLOCKS), dim3(512), gru_args, 0, stream);
}

// Round 19
// 378.637 us; speedup vs baseline: 1.1061x; 1.1061x over previous
//
#include <hip/hip_runtime.h>
#include <hip/hip_cooperative_groups.h>

// ---------- helpers ----------
__device__ __forceinline__ float bf2f(unsigned short u) {
  union { unsigned int i; float f; } v; v.i = ((unsigned int)u) << 16; return v.f;
}
__device__ __forceinline__ unsigned short f2bf(float f) {
  union { float f; unsigned int i; } v; v.f = f;
  unsigned int x = v.i;
  return (unsigned short)((x + 0x7fffu + ((x >> 16) & 1u)) >> 16);
}
__device__ __forceinline__ float sigmf(float x) { return 1.f / (1.f + __expf(-x)); }
__device__ __forceinline__ float tanhfast(float x) {
  float xc = fminf(fmaxf(x, -15.f), 15.f);
  float e = __expf(2.f * xc);
  return (e - 1.f) / (e + 1.f);
}

typedef float f32x4 __attribute__((ext_vector_type(4)));
typedef short short8v __attribute__((ext_vector_type(8)));
typedef short short4v __attribute__((ext_vector_type(4)));

// pack 8 f32 -> 8 bf16 (truncate)
__device__ __forceinline__ short8v pack8(const float* p) {
  union { short8v s; unsigned int u[4]; } r;
#pragma unroll
  for (int i = 0; i < 4; ++i) {
    unsigned int lo = __float_as_uint(p[2 * i]) >> 16;
    unsigned int hi = __float_as_uint(p[2 * i + 1]) & 0xFFFF0000u;
    r.u[i] = hi | lo;
  }
  return r.s;
}

#define KP 1984
#define GRU_BLOCKS 245
#define C1_PLANE 2860

// ---------- fused prep: cvt w_hh [0,2048) | w1frag | w2frag | featpad ----------
__global__ void k_prep(const float* __restrict__ w_hh, unsigned short* __restrict__ whh_bf,
                       const float* __restrict__ w1, const float* __restrict__ b1,
                       unsigned short* __restrict__ w1f,
                       const float* __restrict__ w2, unsigned short* __restrict__ w2f,
                       unsigned short* __restrict__ feat_bf,
                       unsigned long long* __restrict__ hb0,
                       unsigned long long* __restrict__ hb1) {
  const int b = blockIdx.x;
  const int tid = threadIdx.x;
  if (b < 2048) {
    const int n4 = 5880 * 1960 / 4;
    for (int i = b * 256 + tid; i < n4; i += 2048 * 256) {
      float4 v = *reinterpret_cast<const float4*>(&w_hh[i * 4]);
      ushort4 u;
      u.x = f2bf(v.x); u.y = f2bf(v.y); u.z = f2bf(v.z); u.w = f2bf(v.w);
      *reinterpret_cast<ushort4*>(&whh_bf[i * 4]) = u;
    }
  } else if (b < 2072) {
    int idx = (b - 2048) * 256 + tid;
    if (idx < 4 * 3 * 64 * 8) {
      int j = idx & 7, l = (idx >> 3) & 63;
      int rest = idx >> 9;
      int s = rest % 3, ocf = rest / 3;
      int oc = ocf * 16 + (l & 15);
      int k = s * 32 + (l >> 4) * 8 + j;
      float v = 0.f;
      if (k < 64)       v = w1[oc * 81 + (k >> 3) * 9 + (k & 7)];
      else if (k < 72)  v = w1[oc * 81 + 72 + (k - 64)];
      else if (k < 80)  v = w1[oc * 81 + (k - 72) * 9 + 8];
      else if (k == 80) v = w1[oc * 81 + 80];
      else if (k == 81) v = b1[oc];
      w1f[idx] = f2bf(v);
    }
  } else if (b < 2136) {
    int idx = (b - 2072) * 256 + tid;
    if (idx < 32 * 64 * 8) {
      int j = idx & 7, l = (idx >> 3) & 63, s = idx >> 9;
      int oc = l & 15;
      int k = s * 32 + (l >> 4) * 8 + j;
      int t = k >> 6, ch = k & 63, fr = t >> 2, fc = t & 3;
      float v = (oc < 5) ? w2[((oc * 64 + ch) * 4 + fr) * 4 + fc] : 0.f;
      w2f[idx] = f2bf(v);
    }
  } else {
    for (int i = tid; i < 128 * 24; i += 256) {
      int n = i / 24, k = 1960 + i % 24;
      feat_bf[(size_t)n * KP + k] = 0;
    }
    for (int i = tid; i < 3920; i += 256) {
      hb0[i] = 0ull;
      hb1[i] = 0ull;
    }
  }
}

// ---------- kernel 1: conv1 MFMA + pool + sigmoid (proven; conflict-free plane stride) ----------
__global__ __launch_bounds__(256) void k_conv1(const float* __restrict__ x,
                                               const unsigned short* __restrict__ w1f,
                                               unsigned short* __restrict__ pool1) {
  const int n = blockIdx.x, qrg = blockIdx.y;
  const int b = n >> 5, w = n & 31;
  __shared__ __align__(16) unsigned short s_b[4 * C1_PLANE];  // 22880 B
  const int tid = threadIdx.x;
  for (int i = tid; i < 20 * 132; i += 256) {
    int lr = i / 132, lc = i % 132;
    int f = 12 * qrg + lr - 2;
    int t = lc - 2;
    float v = 0.f;
    if (f >= 0 && f < 257 && t >= 0 && t < 128)
      v = x[((size_t)b * 258 + 1 + f) * 2176 + w * 64 + t];
    unsigned short bf = f2bf(v);
#pragma unroll
    for (int m = 0; m < 4; ++m) s_b[m * C1_PLANE + lr * 140 + lc + m] = bf;
  }
  const int lane = tid & 63, wv = tid >> 6;
  short8v bw[4][3];
#pragma unroll
  for (int ocf = 0; ocf < 4; ++ocf)
#pragma unroll
    for (int s = 0; s < 3; ++s)
      bw[ocf][s] = *reinterpret_cast<const short8v*>(&w1f[(((ocf * 3) + s) * 64 + lane) * 8]);
  __syncthreads();

  const int qr = qrg * 4 + wv;
  const int li = lane & 15, g = lane >> 4;

  for (int pgt = 0; pgt < 3; ++pgt) {
    int pg = pgt * 16 + li;
    if (pg > 40) pg = 40;
    f32x4 pm[4];
#pragma unroll
    for (int ocf = 0; ocf < 4; ++ocf) pm[ocf] = (f32x4){-3.4e38f, -3.4e38f, -3.4e38f, -3.4e38f};

    for (int rr = 0; rr < 3; ++rr) {
      const int lrb = 3 * wv + rr;
#pragma unroll
      for (int phi = 0; phi < 3; ++phi) {
        const int c = 3 * pg + phi;
        const int m = (-c) & 3;
        const unsigned short* hb = &s_b[m * C1_PLANE + c + m];
        f32x4 acc[4];
#pragma unroll
        for (int ocf = 0; ocf < 4; ++ocf) acc[ocf] = (f32x4){0.f, 0.f, 0.f, 0.f};
        const unsigned short* p0 = hb + (lrb + g) * 140;
        short8v a0 = __builtin_shufflevector(*reinterpret_cast<const short4v*>(p0),
                                             *reinterpret_cast<const short4v*>(p0 + 4),
                                             0, 1, 2, 3, 4, 5, 6, 7);
#pragma unroll
        for (int ocf = 0; ocf < 4; ++ocf)
          acc[ocf] = __builtin_amdgcn_mfma_f32_16x16x32_bf16(a0, bw[ocf][0], acc[ocf], 0, 0, 0);
        const unsigned short* p1 = p0 + 4 * 140;
        short8v a1 = __builtin_shufflevector(*reinterpret_cast<const short4v*>(p1),
                                             *reinterpret_cast<const short4v*>(p1 + 4),
                                             0, 1, 2, 3, 4, 5, 6, 7);
#pragma unroll
        for (int ocf = 0; ocf < 4; ++ocf)
          acc[ocf] = __builtin_amdgcn_mfma_f32_16x16x32_bf16(a1, bw[ocf][1], acc[ocf], 0, 0, 0);
        short8v a2;
        if (g == 0) {
          const unsigned short* p2 = p0 + 8 * 140;
          a2 = __builtin_shufflevector(*reinterpret_cast<const short4v*>(p2),
                                       *reinterpret_cast<const short4v*>(p2 + 4),
                                       0, 1, 2, 3, 4, 5, 6, 7);
        } else if (g == 1) {
          const unsigned short* pv = &s_b[lrb * 140 + c + 8];
          union { short8v s8; unsigned int u[4]; } r;
          r.u[0] = (unsigned)pv[0]       | ((unsigned)pv[140] << 16);
          r.u[1] = (unsigned)pv[2 * 140] | ((unsigned)pv[3 * 140] << 16);
          r.u[2] = (unsigned)pv[4 * 140] | ((unsigned)pv[5 * 140] << 16);
          r.u[3] = (unsigned)pv[6 * 140] | ((unsigned)pv[7 * 140] << 16);
          a2 = r.s8;
        } else if (g == 2) {
          union { short8v s8; unsigned int u[4]; } r;
          r.u[0] = (unsigned)s_b[(lrb + 8) * 140 + c + 8] | 0x3F800000u;  // corner | bf16(1.0)<<16
          r.u[1] = 0; r.u[2] = 0; r.u[3] = 0;
          a2 = r.s8;
        } else {
          a2 = (short8v){0, 0, 0, 0, 0, 0, 0, 0};
        }
#pragma unroll
        for (int ocf = 0; ocf < 4; ++ocf)
          acc[ocf] = __builtin_amdgcn_mfma_f32_16x16x32_bf16(a2, bw[ocf][2], acc[ocf], 0, 0, 0);
#pragma unroll
        for (int ocf = 0; ocf < 4; ++ocf) {
#pragma unroll
          for (int i = 0; i < 4; ++i) pm[ocf][i] = fmaxf(pm[ocf][i], acc[ocf][i]);
        }
      }
    }
#pragma unroll
    for (int ocf = 0; ocf < 4; ++ocf) {
#pragma unroll
      for (int i = 0; i < 4; ++i) {
        int pg2 = pgt * 16 + g * 4 + i;
        if (pg2 <= 40) {
          int oc = ocf * 16 + li;
          pool1[(((size_t)n * 84 + qr) * 41 + pg2) * 64 + oc] = f2bf(sigmf(pm[ocf][i]));
        }
      }
    }
  }
}

// ---------- kernel 2: conv2 MFMA, LDS-staged A, weights in regs ----------
__global__ __launch_bounds__(128, 2) void k_conv2(const unsigned short* __restrict__ pool1,
                                                  const unsigned short* __restrict__ w2f,
                                                  const float* __restrict__ b2,
                                                  unsigned short* __restrict__ feat_bf) {
  const int n = blockIdx.x, qg = blockIdx.y;
  __shared__ __align__(16) unsigned short s_a[9 * 46 * 64];
  const int tid = threadIdx.x;
  const int lane = tid & 63, wv = tid >> 6;
  short8v bwr[32];
#pragma unroll
  for (int s = 0; s < 32; ++s)
    bwr[s] = *reinterpret_cast<const short8v*>(&w2f[(s * 64 + lane) * 8]);
  const int r0 = 6 * qg - 2;
  for (int idx = tid; idx < 9 * 46 * 8; idx += 128) {
    int row = idx / (46 * 8);
    int rem = idx - row * (46 * 8);
    int lc = rem >> 3, cp = rem & 7;
    int gr = r0 + row, gc = lc - 2;
    short8v v = {0, 0, 0, 0, 0, 0, 0, 0};
    if ((unsigned)gr < 84u && (unsigned)gc < 41u)
      v = *reinterpret_cast<const short8v*>(&pool1[(((size_t)n * 84 + gr) * 41 + gc) * 64 + cp * 8]);
    int rot = (cp * 8 + lc * 8) & 63;
    *reinterpret_cast<short8v*>(&s_a[(row * 46 + lc) * 64 + rot]) = v;
  }
  __syncthreads();

  const int q = qg * 2 + wv;
  const int li = lane & 15, g = lane >> 4;
  const int pg = li > 13 ? 13 : li;
  f32x4 pm = (f32x4){-3.4e38f, -3.4e38f, -3.4e38f, -3.4e38f};

  for (int rr = 0; rr < 3; ++rr) {
#pragma unroll
    for (int phi = 0; phi < 3; ++phi) {
      f32x4 acc[4];
#pragma unroll
      for (int i = 0; i < 4; ++i) acc[i] = (f32x4){0.f, 0.f, 0.f, 0.f};
#pragma unroll
      for (int s = 0; s < 32; ++s) {
        const int t = s >> 1, h = s & 1;
        const int fr = t >> 2, fc = t & 3;
        const int srow = 3 * wv + rr + fr;
        const int lc = 3 * pg + phi + fc;
        const int rot = (h * 32 + g * 8 + lc * 8) & 63;
        short8v a = *reinterpret_cast<const short8v*>(&s_a[(srow * 46 + lc) * 64 + rot]);
        acc[s & 3] = __builtin_amdgcn_mfma_f32_16x16x32_bf16(a, bwr[s], acc[s & 3], 0, 0, 0);
      }
      f32x4 sum;
#pragma unroll
      for (int i = 0; i < 4; ++i) sum[i] = (acc[0][i] + acc[1][i]) + (acc[2][i] + acc[3][i]);
#pragma unroll
      for (int i = 0; i < 4; ++i) pm[i] = fmaxf(pm[i], sum[i]);
    }
  }
  if (li < 5) {
#pragma unroll
    for (int i = 0; i < 4; ++i) {
      int pq = g * 4 + i;
      if (pq < 14)
        feat_bf[(size_t)n * KP + li * 392 + q * 14 + pq] = f2bf(sigmf(pm[i] + b2[li]));
    }
  }
}

// ---------- kernel 4: gi MFMA GEMM (reads w_ih f32 directly, inline bf16 pack) ----------
__global__ __launch_bounds__(256) void k_gi(const unsigned short* __restrict__ feat_bf,
                                            const float* __restrict__ w_ih,
                                            const float* __restrict__ b_ih,
                                            float* __restrict__ gi) {
  const int bx = blockIdx.x, bm = blockIdx.y;
  const int w = threadIdx.x >> 6, lane = threadIdx.x & 63;
  const int li = lane & 15, g = lane >> 4;
  const int j = bx * 16 + li;
  const int jc = j < 5880 ? j : 5879;
  const unsigned short* ap = feat_bf + (size_t)(bm * 64 + w * 16 + li) * KP + g * 8;
  const float* bp = w_ih + (size_t)jc * 1960 + g * 8;
  const short8v z8 = {0, 0, 0, 0, 0, 0, 0, 0};
  f32x4 acc0 = (f32x4){0.f, 0.f, 0.f, 0.f};
  f32x4 acc1 = (f32x4){0.f, 0.f, 0.f, 0.f};
  for (int kc = 0; kc < 62; kc += 2) {
    short8v a0 = *reinterpret_cast<const short8v*>(ap + kc * 32);
    short8v a1 = *reinterpret_cast<const short8v*>(ap + kc * 32 + 32);
    short8v b0 = pack8(bp + kc * 32);
    short8v b1 = (kc != 60 || g == 0) ? pack8(bp + kc * 32 + 32) : z8;
    acc0 = __builtin_amdgcn_mfma_f32_16x16x32_bf16(a0, b0, acc0, 0, 0, 0);
    acc1 = __builtin_amdgcn_mfma_f32_16x16x32_bf16(a1, b1, acc1, 0, 0, 0);
  }
  if (j < 5880) {
    const float bi = b_ih[j];
    const int n0 = bm * 64 + w * 16 + g * 4;
#pragma unroll
    for (int i = 0; i < 4; ++i)
      gi[(size_t)(n0 + i) * 5880 + j] = acc0[i] + acc1[i] + bi;
  }
}

// ---------- kernel 5: persistent GRU (bf16 preload, 3 barriers/step, fused fc) ----------
__global__ __launch_bounds__(512) void k_gru(const unsigned short* __restrict__ whh,
                                             const float* __restrict__ b_hh,
                                             const float* __restrict__ gi,
                                             const float* __restrict__ hx0,
                                             unsigned long long* __restrict__ hb0,
                                             unsigned long long* __restrict__ hb1,
                                             const float* __restrict__ fc_w,
                                             const float* __restrict__ fc_b,
                                             const int* __restrict__ labels,
                                             float* __restrict__ out) {
  __shared__ __align__(16) unsigned short s_w[2 * 62 * 64 * 8];  // 126976 B
  __shared__ __align__(16) unsigned short s_h[4 * 1984];         // 15872 B
  __shared__ float s_part[4 * 2 * 64 * 4];                        // 8192 B
  __shared__ float s_gi[2][96];
  const int tid = threadIdx.x;
  const int bid = blockIdx.x;
  const int k0 = bid * 8;
  const int lane = tid & 63, wv = tid >> 6;
  const int li = lane & 15, g2 = lane >> 4;

  // preload w A-fragments from bf16 global (consecutive threads -> consecutive LDS 16B)
  for (int idx = tid; idx < 2 * 62 * 64; idx += 512) {
    int mt = idx / 3968;
    int rem = idx - mt * 3968;
    int kc = rem >> 6, l = rem & 63;
    int lli = l & 15, lg2 = l >> 4;
    int k = kc * 32 + lg2 * 8;
    short8v v = {0, 0, 0, 0, 0, 0, 0, 0};
    bool rowok = (mt == 0) ? true : (lli < 8);
    if (rowok && k < 1960) {
      int g = (mt == 0) ? (lli >> 3) : 2;
      int kk = (mt == 0) ? (lli & 7) : lli;
      v = *reinterpret_cast<const short8v*>(&whh[(size_t)(g * 1960 + k0 + kk) * 1960 + k]);
    }
    *reinterpret_cast<short8v*>(&s_w[(size_t)idx * 8]) = v;
  }
  for (int i = tid; i < 4 * 992; i += 512) reinterpret_cast<unsigned int*>(s_h)[i] = 0u;

  float hp0 = 0.f, hp1 = 0.f, bhr0 = 0, bhr1 = 0, bhz0 = 0, bhz1 = 0, bhn0 = 0, bhn1 = 0;
  if (tid < 16) {
    int cb = tid >> 2, p = tid & 3;
    int k = k0 + 2 * p;
    hp0 = hx0[cb * 1960 + k];
    hp1 = hx0[cb * 1960 + k + 1];
    bhr0 = b_hh[k];         bhr1 = b_hh[k + 1];
    bhz0 = b_hh[1960 + k];  bhz1 = b_hh[1960 + k + 1];
    bhn0 = b_hh[3920 + k];  bhn1 = b_hh[3920 + k + 1];
  }
  __syncthreads();

  for (int t = 0; t < 32; ++t) {
    // ---- stage h (batched tagged poll for t>=1) + gi prefetch ----
    if (t == 0) {
      for (int i = tid; i < 7840; i += 512) {
        int b = i / 1960, k = i - b * 1960;
        s_h[b * 1984 + k] = f2bf(hx0[i]);
      }
    } else {
      const unsigned long long* hin = (t & 1) ? hb1 : hb0;
      unsigned pend = 0;
#pragma unroll
      for (int r = 0; r < 8; ++r)
        if (tid + (r << 9) < 3920) pend |= (1u << r);
      while (pend) {
        unsigned long long v[8];
#pragma unroll
        for (int r = 0; r < 8; ++r)
          if (pend & (1u << r))
            v[r] = __hip_atomic_load(&hin[tid + (r << 9)], __ATOMIC_RELAXED,
                                     __HIP_MEMORY_SCOPE_AGENT);
#pragma unroll
        for (int r = 0; r < 8; ++r) {
          if ((pend & (1u << r)) && (unsigned)(v[r] >> 32) >= (unsigned)t) {
            int i = tid + (r << 9);
            int b = i / 980, kp = i - b * 980;
            reinterpret_cast<unsigned int*>(s_h)[b * 992 + kp] = (unsigned)v[r];
            pend &= ~(1u << r);
          }
        }
        if (pend) __builtin_amdgcn_s_sleep(0);
      }
    }
    if (tid < 96) {
      int gg = tid >> 5, bb = (tid >> 3) & 3, kk = tid & 7;
      s_gi[t & 1][tid] = gi[(size_t)(bb * 32 + t) * 5880 + gg * 1960 + k0 + kk];
    }
    __syncthreads();  // barrier A: stage complete

    // ---- MFMA dot (waves 0-3) ----
    if (wv < 4) {
      f32x4 acc0 = (f32x4){0.f, 0.f, 0.f, 0.f};
      f32x4 acc1 = (f32x4){0.f, 0.f, 0.f, 0.f};
      for (int kc = wv; kc < 62; kc += 4) {
        short8v bfr = *reinterpret_cast<const short8v*>(&s_h[(li & 3) * 1984 + kc * 32 + g2 * 8]);
        short8v a0 = *reinterpret_cast<const short8v*>(&s_w[((size_t)kc * 64 + lane) * 8]);
        short8v a1 = *reinterpret_cast<const short8v*>(&s_w[((size_t)(62 + kc) * 64 + lane) * 8]);
        acc0 = __builtin_amdgcn_mfma_f32_16x16x32_bf16(a0, bfr, acc0, 0, 0, 0);
        acc1 = __builtin_amdgcn_mfma_f32_16x16x32_bf16(a1, bfr, acc1, 0, 0, 0);
      }
      *reinterpret_cast<f32x4*>(&s_part[((wv * 2 + 0) * 64 + lane) * 4]) = acc0;
      *reinterpret_cast<f32x4*>(&s_part[((wv * 2 + 1) * 64 + lane) * 4]) = acc1;
    }
    __syncthreads();  // barrier B: s_part ready

    // ---- update (16 threads) + publish tagged ----
    unsigned long long* hout = (t & 1) ? hb0 : hb1;
    if (tid < 16) {
      const int cb = tid >> 2, p = tid & 3;
      const int kk = 2 * p;
      auto psum = [&](int mt, int m) -> float {
        int base = mt * 256 + ((m >> 2) * 16 + cb) * 4 + (m & 3);
        return ((s_part[base] + s_part[base + 512]) +
                (s_part[base + 1024] + s_part[base + 1536]));
      };
      float ghr0 = psum(0, kk),     ghr1 = psum(0, kk + 1);
      float ghz0 = psum(0, 8 + kk), ghz1 = psum(0, 8 + kk + 1);
      float ghn0 = psum(1, kk),     ghn1 = psum(1, kk + 1);
      float r0 = sigmf(s_gi[t & 1][cb * 8 + kk] + ghr0 + bhr0);
      float z0 = sigmf(s_gi[t & 1][32 + cb * 8 + kk] + ghz0 + bhz0);
      float n0 = tanhfast(s_gi[t & 1][64 + cb * 8 + kk] + r0 * (ghn0 + bhn0));
      float h0v = (1.f - z0) * n0 + z0 * hp0;
      float r1 = sigmf(s_gi[t & 1][cb * 8 + kk + 1] + ghr1 + bhr1);
      float z1 = sigmf(s_gi[t & 1][32 + cb * 8 + kk + 1] + ghz1 + bhz1);
      float n1 = tanhfast(s_gi[t & 1][64 + cb * 8 + kk + 1] + r1 * (ghn1 + bhn1));
      float h1v = (1.f - z1) * n1 + z1 * hp1;
      hp0 = h0v; hp1 = h1v;
      unsigned long long packed =
          ((unsigned long long)(unsigned)(t + 1) << 32) |
          (unsigned long long)((unsigned)f2bf(h0v) | ((unsigned)f2bf(h1v) << 16));
      __hip_atomic_store(&hout[cb * 980 + (k0 >> 1) + p], packed,
                         __ATOMIC_RELAXED, __HIP_MEMORY_SCOPE_AGENT);
    }
    __syncthreads();  // barrier C: keep non-update waves from racing into next poll
  }

  // ---- fused fc + softmax (block 0 only) ----
  if (bid == 0) {
    unsigned pend = 0;
#pragma unroll
    for (int r = 0; r < 8; ++r)
      if (tid + (r << 9) < 3920) pend |= (1u << r);
    while (pend) {
      unsigned long long v[8];
#pragma unroll
      for (int r = 0; r < 8; ++r)
        if (pend & (1u << r))
          v[r] = __hip_atomic_load(&hb0[tid + (r << 9)], __ATOMIC_RELAXED,
                                   __HIP_MEMORY_SCOPE_AGENT);
#pragma unroll
      for (int r = 0; r < 8; ++r) {
        if ((pend & (1u << r)) && (unsigned)(v[r] >> 32) >= 32u) {
          int i = tid + (r << 9);
          int b = i / 980, kp = i - b * 980;
          reinterpret_cast<unsigned int*>(s_h)[b * 992 + kp] = (unsigned)v[r];
          pend &= ~(1u << r);
        }
      }
      if (pend) __builtin_amdgcn_s_sleep(0);
    }
    __syncthreads();
    if (tid < 64) {
      const int l = tid;
      float acc[8];
#pragma unroll
      for (int i = 0; i < 8; ++i) acc[i] = 0.f;
      for (int k = l; k < 1960; k += 64) {
        const float w0 = fc_w[k], w1 = fc_w[1960 + k];
#pragma unroll
        for (int b = 0; b < 4; ++b) {
          const float hv = bf2f(s_h[b * 1984 + k]);
          acc[b * 2 + 0] += hv * w0;
          acc[b * 2 + 1] += hv * w1;
        }
      }
#pragma unroll
      for (int i = 0; i < 8; ++i) {
        float a = acc[i];
#pragma unroll
        for (int off = 32; off; off >>= 1) a += __shfl_xor(a, off, 64);
        acc[i] = a;
      }
      if (l == 0) {
#pragma unroll
        for (int b = 0; b < 4; ++b) {
          const float l0 = acc[b * 2] + fc_b[0], l1 = acc[b * 2 + 1] + fc_b[1];
          const float m = fmaxf(l0, l1);
          const float e0 = __expf(l0 - m), e1 = __expf(l1 - m);
          const float s = e0 + e1;
          out[b * 2 + 0] = e0 / s;
          out[b * 2 + 1] = e1 / s;
        }
        for (int i = 0; i < 4; ++i) out[8 + i] = (float)labels[i];
      }
    }
  }
}

extern "C" void kernel_launch(void* const* d_in, const int* in_sizes, int n_in,
                              void* d_out, int out_size, void* d_ws, size_t ws_size,
                              hipStream_t stream) {
  const float* x       = (const float*)d_in[0];
  const float* hx0     = (const float*)d_in[1];
  const int*   labels  = (const int*)d_in[2];
  const float* conv1_w = (const float*)d_in[3];
  const float* conv1_b = (const float*)d_in[4];
  const float* conv2_w = (const float*)d_in[5];
  const float* conv2_b = (const float*)d_in[6];
  const float* w_ih    = (const float*)d_in[7];
  const float* w_hh    = (const float*)d_in[8];
  const float* b_ih    = (const float*)d_in[9];
  const float* b_hh    = (const float*)d_in[10];
  const float* fc_w    = (const float*)d_in[11];
  const float* fc_b    = (const float*)d_in[12];

  char* ws = (char*)d_ws;
  size_t off = 0;
  unsigned short* pool1 = (unsigned short*)(ws + off); off += (size_t)128 * 84 * 41 * 64 * 2;  // 56.4MB
  unsigned short* feat_bf = (unsigned short*)(ws + off); off += (size_t)128 * KP * 2;          // 0.5MB
  float* gi    = (float*)(ws + off); off += (size_t)128 * 5880 * 4;                            // 3.0MB
  unsigned short* whh_bf = (unsigned short*)(ws + off); off += (size_t)5880 * 1960 * 2;        // 23.0MB
  unsigned long long* hb0 = (unsigned long long*)(ws + off); off += (size_t)4 * 980 * 8;       // 31.4KB
  unsigned long long* hb1 = (unsigned long long*)(ws + off); off += (size_t)4 * 980 * 8;       // 31.4KB
  unsigned short* w1f = (unsigned short*)(ws + off); off += (size_t)4 * 3 * 64 * 8 * 2;        // 12KB
  unsigned short* w2f = (unsigned short*)(ws + off); off += (size_t)32 * 64 * 8 * 2;           // 32KB

  k_prep<<<2137, 256, 0, stream>>>(w_hh, whh_bf, conv1_w, conv1_b, w1f,
                                   conv2_w, w2f, feat_bf, hb0, hb1);

  dim3 g1(128, 21);
  k_conv1<<<g1, 256, 0, stream>>>(x, w1f, pool1);

  dim3 g2(128, 14);
  k_conv2<<<g2, 128, 0, stream>>>(pool1, w2f, conv2_b, feat_bf);

  dim3 g3(368, 2);
  k_gi<<<g3, 256, 0, stream>>>(feat_bf, w_ih, b_ih, gi);

  // all 32 GRU steps + fused fc; final h_32 in hb0; out written by block 0
  void* gru_args[] = {(void*)&whh_bf, (void*)&b_hh, (void*)&gi, (void*)&hx0,
                      (void*)&hb0, (void*)&hb1, (void*)&fc_w, (void*)&fc_b,
                      (void*)&labels, (void*)&d_out};
  hipLaunchCooperativeKernel((const void*)k_gru, dim3(GRU_BLOCKS), dim3(512), gru_args, 0, stream);
}

// Round 20
// 373.529 us; speedup vs baseline: 1.1213x; 1.0137x over previous
//
#include <hip/hip_runtime.h>
#include <hip/hip_cooperative_groups.h>

// ---------- helpers ----------
__device__ __forceinline__ float bf2f(unsigned short u) {
  union { unsigned int i; float f; } v; v.i = ((unsigned int)u) << 16; return v.f;
}
__device__ __forceinline__ unsigned short f2bf(float f) {
  union { float f; unsigned int i; } v; v.f = f;
  unsigned int x = v.i;
  return (unsigned short)((x + 0x7fffu + ((x >> 16) & 1u)) >> 16);
}
__device__ __forceinline__ float sigmf(float x) { return 1.f / (1.f + __expf(-x)); }
__device__ __forceinline__ float tanhfast(float x) {
  float xc = fminf(fmaxf(x, -15.f), 15.f);
  float e = __expf(2.f * xc);
  return (e - 1.f) / (e + 1.f);
}

typedef float f32x4 __attribute__((ext_vector_type(4)));
typedef short short8v __attribute__((ext_vector_type(8)));
typedef short short4v __attribute__((ext_vector_type(4)));

// pack 8 f32 -> 8 bf16 (truncate)
__device__ __forceinline__ short8v pack8(const float* p) {
  union { short8v s; unsigned int u[4]; } r;
#pragma unroll
  for (int i = 0; i < 4; ++i) {
    unsigned int lo = __float_as_uint(p[2 * i]) >> 16;
    unsigned int hi = __float_as_uint(p[2 * i + 1]) & 0xFFFF0000u;
    r.u[i] = hi | lo;
  }
  return r.s;
}

#define KP 1984
#define GRU_BLOCKS 245
#define C1_PLANE 2860

// ---------- fused prep: cvt w_hh [0,2048) | w1frag | w2frag | featpad ----------
__global__ void k_prep(const float* __restrict__ w_hh, unsigned short* __restrict__ whh_bf,
                       const float* __restrict__ w1, const float* __restrict__ b1,
                       unsigned short* __restrict__ w1f,
                       const float* __restrict__ w2, unsigned short* __restrict__ w2f,
                       unsigned short* __restrict__ feat_bf,
                       unsigned long long* __restrict__ hb0,
                       unsigned long long* __restrict__ hb1) {
  const int b = blockIdx.x;
  const int tid = threadIdx.x;
  if (b < 2048) {
    const int n4 = 5880 * 1960 / 4;
    for (int i = b * 256 + tid; i < n4; i += 2048 * 256) {
      float4 v = *reinterpret_cast<const float4*>(&w_hh[i * 4]);
      ushort4 u;
      u.x = f2bf(v.x); u.y = f2bf(v.y); u.z = f2bf(v.z); u.w = f2bf(v.w);
      *reinterpret_cast<ushort4*>(&whh_bf[i * 4]) = u;
    }
  } else if (b < 2072) {
    int idx = (b - 2048) * 256 + tid;
    if (idx < 4 * 3 * 64 * 8) {
      int j = idx & 7, l = (idx >> 3) & 63;
      int rest = idx >> 9;
      int s = rest % 3, ocf = rest / 3;
      int oc = ocf * 16 + (l & 15);
      int k = s * 32 + (l >> 4) * 8 + j;
      float v = 0.f;
      if (k < 64)       v = w1[oc * 81 + (k >> 3) * 9 + (k & 7)];
      else if (k < 72)  v = w1[oc * 81 + 72 + (k - 64)];
      else if (k < 80)  v = w1[oc * 81 + (k - 72) * 9 + 8];
      else if (k == 80) v = w1[oc * 81 + 80];
      else if (k == 81) v = b1[oc];
      w1f[idx] = f2bf(v);
    }
  } else if (b < 2136) {
    int idx = (b - 2072) * 256 + tid;
    if (idx < 32 * 64 * 8) {
      int j = idx & 7, l = (idx >> 3) & 63, s = idx >> 9;
      int oc = l & 15;
      int k = s * 32 + (l >> 4) * 8 + j;
      int t = k >> 6, ch = k & 63, fr = t >> 2, fc = t & 3;
      float v = (oc < 5) ? w2[((oc * 64 + ch) * 4 + fr) * 4 + fc] : 0.f;
      w2f[idx] = f2bf(v);
    }
  } else {
    for (int i = tid; i < 128 * 24; i += 256) {
      int n = i / 24, k = 1960 + i % 24;
      feat_bf[(size_t)n * KP + k] = 0;
    }
    for (int i = tid; i < 3920; i += 256) {
      hb0[i] = 0ull;
      hb1[i] = 0ull;
    }
  }
}

// ---------- kernel 1: conv1 MFMA + pool + sigmoid (proven; conflict-free plane stride) ----------
__global__ __launch_bounds__(256) void k_conv1(const float* __restrict__ x,
                                               const unsigned short* __restrict__ w1f,
                                               unsigned short* __restrict__ pool1) {
  const int n = blockIdx.x, qrg = blockIdx.y;
  const int b = n >> 5, w = n & 31;
  __shared__ __align__(16) unsigned short s_b[4 * C1_PLANE];  // 22880 B
  const int tid = threadIdx.x;
  for (int i = tid; i < 20 * 132; i += 256) {
    int lr = i / 132, lc = i % 132;
    int f = 12 * qrg + lr - 2;
    int t = lc - 2;
    float v = 0.f;
    if (f >= 0 && f < 257 && t >= 0 && t < 128)
      v = x[((size_t)b * 258 + 1 + f) * 2176 + w * 64 + t];
    unsigned short bf = f2bf(v);
#pragma unroll
    for (int m = 0; m < 4; ++m) s_b[m * C1_PLANE + lr * 140 + lc + m] = bf;
  }
  const int lane = tid & 63, wv = tid >> 6;
  short8v bw[4][3];
#pragma unroll
  for (int ocf = 0; ocf < 4; ++ocf)
#pragma unroll
    for (int s = 0; s < 3; ++s)
      bw[ocf][s] = *reinterpret_cast<const short8v*>(&w1f[(((ocf * 3) + s) * 64 + lane) * 8]);
  __syncthreads();

  const int qr = qrg * 4 + wv;
  const int li = lane & 15, g = lane >> 4;

  for (int pgt = 0; pgt < 3; ++pgt) {
    int pg = pgt * 16 + li;
    if (pg > 40) pg = 40;
    f32x4 pm[4];
#pragma unroll
    for (int ocf = 0; ocf < 4; ++ocf) pm[ocf] = (f32x4){-3.4e38f, -3.4e38f, -3.4e38f, -3.4e38f};

    for (int rr = 0; rr < 3; ++rr) {
      const int lrb = 3 * wv + rr;
#pragma unroll
      for (int phi = 0; phi < 3; ++phi) {
        const int c = 3 * pg + phi;
        const int m = (-c) & 3;
        const unsigned short* hb = &s_b[m * C1_PLANE + c + m];
        f32x4 acc[4];
#pragma unroll
        for (int ocf = 0; ocf < 4; ++ocf) acc[ocf] = (f32x4){0.f, 0.f, 0.f, 0.f};
        const unsigned short* p0 = hb + (lrb + g) * 140;
        short8v a0 = __builtin_shufflevector(*reinterpret_cast<const short4v*>(p0),
                                             *reinterpret_cast<const short4v*>(p0 + 4),
                                             0, 1, 2, 3, 4, 5, 6, 7);
#pragma unroll
        for (int ocf = 0; ocf < 4; ++ocf)
          acc[ocf] = __builtin_amdgcn_mfma_f32_16x16x32_bf16(a0, bw[ocf][0], acc[ocf], 0, 0, 0);
        const unsigned short* p1 = p0 + 4 * 140;
        short8v a1 = __builtin_shufflevector(*reinterpret_cast<const short4v*>(p1),
                                             *reinterpret_cast<const short4v*>(p1 + 4),
                                             0, 1, 2, 3, 4, 5, 6, 7);
#pragma unroll
        for (int ocf = 0; ocf < 4; ++ocf)
          acc[ocf] = __builtin_amdgcn_mfma_f32_16x16x32_bf16(a1, bw[ocf][1], acc[ocf], 0, 0, 0);
        short8v a2;
        if (g == 0) {
          const unsigned short* p2 = p0 + 8 * 140;
          a2 = __builtin_shufflevector(*reinterpret_cast<const short4v*>(p2),
                                       *reinterpret_cast<const short4v*>(p2 + 4),
                                       0, 1, 2, 3, 4, 5, 6, 7);
        } else if (g == 1) {
          const unsigned short* pv = &s_b[lrb * 140 + c + 8];
          union { short8v s8; unsigned int u[4]; } r;
          r.u[0] = (unsigned)pv[0]       | ((unsigned)pv[140] << 16);
          r.u[1] = (unsigned)pv[2 * 140] | ((unsigned)pv[3 * 140] << 16);
          r.u[2] = (unsigned)pv[4 * 140] | ((unsigned)pv[5 * 140] << 16);
          r.u[3] = (unsigned)pv[6 * 140] | ((unsigned)pv[7 * 140] << 16);
          a2 = r.s8;
        } else if (g == 2) {
          union { short8v s8; unsigned int u[4]; } r;
          r.u[0] = (unsigned)s_b[(lrb + 8) * 140 + c + 8] | 0x3F800000u;  // corner | bf16(1.0)<<16
          r.u[1] = 0; r.u[2] = 0; r.u[3] = 0;
          a2 = r.s8;
        } else {
          a2 = (short8v){0, 0, 0, 0, 0, 0, 0, 0};
        }
#pragma unroll
        for (int ocf = 0; ocf < 4; ++ocf)
          acc[ocf] = __builtin_amdgcn_mfma_f32_16x16x32_bf16(a2, bw[ocf][2], acc[ocf], 0, 0, 0);
#pragma unroll
        for (int ocf = 0; ocf < 4; ++ocf) {
#pragma unroll
          for (int i = 0; i < 4; ++i) pm[ocf][i] = fmaxf(pm[ocf][i], acc[ocf][i]);
        }
      }
    }
#pragma unroll
    for (int ocf = 0; ocf < 4; ++ocf) {
#pragma unroll
      for (int i = 0; i < 4; ++i) {
        int pg2 = pgt * 16 + g * 4 + i;
        if (pg2 <= 40) {
          int oc = ocf * 16 + li;
          pool1[(((size_t)n * 84 + qr) * 41 + pg2) * 64 + oc] = f2bf(sigmf(pm[ocf][i]));
        }
      }
    }
  }
}

// ---------- kernel 2: conv2 MFMA, LDS-staged A, weights in regs ----------
__global__ __launch_bounds__(128, 2) void k_conv2(const unsigned short* __restrict__ pool1,
                                                  const unsigned short* __restrict__ w2f,
                                                  const float* __restrict__ b2,
                                                  unsigned short* __restrict__ feat_bf) {
  const int n = blockIdx.x, qg = blockIdx.y;
  __shared__ __align__(16) unsigned short s_a[9 * 46 * 64];
  const int tid = threadIdx.x;
  const int lane = tid & 63, wv = tid >> 6;
  short8v bwr[32];
#pragma unroll
  for (int s = 0; s < 32; ++s)
    bwr[s] = *reinterpret_cast<const short8v*>(&w2f[(s * 64 + lane) * 8]);
  const int r0 = 6 * qg - 2;
  for (int idx = tid; idx < 9 * 46 * 8; idx += 128) {
    int row = idx / (46 * 8);
    int rem = idx - row * (46 * 8);
    int lc = rem >> 3, cp = rem & 7;
    int gr = r0 + row, gc = lc - 2;
    short8v v = {0, 0, 0, 0, 0, 0, 0, 0};
    if ((unsigned)gr < 84u && (unsigned)gc < 41u)
      v = *reinterpret_cast<const short8v*>(&pool1[(((size_t)n * 84 + gr) * 41 + gc) * 64 + cp * 8]);
    int rot = (cp * 8 + lc * 8) & 63;
    *reinterpret_cast<short8v*>(&s_a[(row * 46 + lc) * 64 + rot]) = v;
  }
  __syncthreads();

  const int q = qg * 2 + wv;
  const int li = lane & 15, g = lane >> 4;
  const int pg = li > 13 ? 13 : li;
  f32x4 pm = (f32x4){-3.4e38f, -3.4e38f, -3.4e38f, -3.4e38f};

  for (int rr = 0; rr < 3; ++rr) {
#pragma unroll
    for (int phi = 0; phi < 3; ++phi) {
      f32x4 acc[4];
#pragma unroll
      for (int i = 0; i < 4; ++i) acc[i] = (f32x4){0.f, 0.f, 0.f, 0.f};
#pragma unroll
      for (int s = 0; s < 32; ++s) {
        const int t = s >> 1, h = s & 1;
        const int fr = t >> 2, fc = t & 3;
        const int srow = 3 * wv + rr + fr;
        const int lc = 3 * pg + phi + fc;
        const int rot = (h * 32 + g * 8 + lc * 8) & 63;
        short8v a = *reinterpret_cast<const short8v*>(&s_a[(srow * 46 + lc) * 64 + rot]);
        acc[s & 3] = __builtin_amdgcn_mfma_f32_16x16x32_bf16(a, bwr[s], acc[s & 3], 0, 0, 0);
      }
      f32x4 sum;
#pragma unroll
      for (int i = 0; i < 4; ++i) sum[i] = (acc[0][i] + acc[1][i]) + (acc[2][i] + acc[3][i]);
#pragma unroll
      for (int i = 0; i < 4; ++i) pm[i] = fmaxf(pm[i], sum[i]);
    }
  }
  if (li < 5) {
#pragma unroll
    for (int i = 0; i < 4; ++i) {
      int pq = g * 4 + i;
      if (pq < 14)
        feat_bf[(size_t)n * KP + li * 392 + q * 14 + pq] = f2bf(sigmf(pm[i] + b2[li]));
    }
  }
}

// ---------- kernel 4: gi MFMA GEMM (reads w_ih f32 directly, inline bf16 pack) ----------
__global__ __launch_bounds__(256) void k_gi(const unsigned short* __restrict__ feat_bf,
                                            const float* __restrict__ w_ih,
                                            const float* __restrict__ b_ih,
                                            float* __restrict__ gi) {
  const int bx = blockIdx.x, bm = blockIdx.y;
  const int w = threadIdx.x >> 6, lane = threadIdx.x & 63;
  const int li = lane & 15, g = lane >> 4;
  const int j = bx * 16 + li;
  const int jc = j < 5880 ? j : 5879;
  const unsigned short* ap = feat_bf + (size_t)(bm * 64 + w * 16 + li) * KP + g * 8;
  const float* bp = w_ih + (size_t)jc * 1960 + g * 8;
  const short8v z8 = {0, 0, 0, 0, 0, 0, 0, 0};
  f32x4 acc0 = (f32x4){0.f, 0.f, 0.f, 0.f};
  f32x4 acc1 = (f32x4){0.f, 0.f, 0.f, 0.f};
  for (int kc = 0; kc < 62; kc += 2) {
    short8v a0 = *reinterpret_cast<const short8v*>(ap + kc * 32);
    short8v a1 = *reinterpret_cast<const short8v*>(ap + kc * 32 + 32);
    short8v b0 = pack8(bp + kc * 32);
    short8v b1 = (kc != 60 || g == 0) ? pack8(bp + kc * 32 + 32) : z8;
    acc0 = __builtin_amdgcn_mfma_f32_16x16x32_bf16(a0, b0, acc0, 0, 0, 0);
    acc1 = __builtin_amdgcn_mfma_f32_16x16x32_bf16(a1, b1, acc1, 0, 0, 0);
  }
  if (j < 5880) {
    const float bi = b_ih[j];
    const int n0 = bm * 64 + w * 16 + g * 4;
#pragma unroll
    for (int i = 0; i < 4; ++i)
      gi[(size_t)(n0 + i) * 5880 + j] = acc0[i] + acc1[i] + bi;
  }
}

// ---------- kernel 5: persistent GRU (bf16 preload, gi prefetch under dot, fused fc) ----------
__global__ __launch_bounds__(512) void k_gru(const unsigned short* __restrict__ whh,
                                             const float* __restrict__ b_hh,
                                             const float* __restrict__ gi,
                                             const float* __restrict__ hx0,
                                             unsigned long long* __restrict__ hb0,
                                             unsigned long long* __restrict__ hb1,
                                             const float* __restrict__ fc_w,
                                             const float* __restrict__ fc_b,
                                             const int* __restrict__ labels,
                                             float* __restrict__ out) {
  __shared__ __align__(16) unsigned short s_w[2 * 62 * 64 * 8];  // 126976 B
  __shared__ __align__(16) unsigned short s_h[4 * 1984];         // 15872 B
  __shared__ float s_part[4 * 2 * 64 * 4];                        // 8192 B
  __shared__ float s_gi[2][96];
  const int tid = threadIdx.x;
  const int bid = blockIdx.x;
  const int k0 = bid * 8;
  const int lane = tid & 63, wv = tid >> 6;
  const int li = lane & 15, g2 = lane >> 4;

  // preload w A-fragments from bf16 global (consecutive threads -> consecutive LDS 16B)
  for (int idx = tid; idx < 2 * 62 * 64; idx += 512) {
    int mt = idx / 3968;
    int rem = idx - mt * 3968;
    int kc = rem >> 6, l = rem & 63;
    int lli = l & 15, lg2 = l >> 4;
    int k = kc * 32 + lg2 * 8;
    short8v v = {0, 0, 0, 0, 0, 0, 0, 0};
    bool rowok = (mt == 0) ? true : (lli < 8);
    if (rowok && k < 1960) {
      int g = (mt == 0) ? (lli >> 3) : 2;
      int kk = (mt == 0) ? (lli & 7) : lli;
      v = *reinterpret_cast<const short8v*>(&whh[(size_t)(g * 1960 + k0 + kk) * 1960 + k]);
    }
    *reinterpret_cast<short8v*>(&s_w[(size_t)idx * 8]) = v;
  }
  for (int i = tid; i < 4 * 992; i += 512) reinterpret_cast<unsigned int*>(s_h)[i] = 0u;

  float hp0 = 0.f, hp1 = 0.f, bhr0 = 0, bhr1 = 0, bhz0 = 0, bhz1 = 0, bhn0 = 0, bhn1 = 0;
  if (tid < 16) {
    int cb = tid >> 2, p = tid & 3;
    int k = k0 + 2 * p;
    hp0 = hx0[cb * 1960 + k];
    hp1 = hx0[cb * 1960 + k + 1];
    bhr0 = b_hh[k];         bhr1 = b_hh[k + 1];
    bhz0 = b_hh[1960 + k];  bhz1 = b_hh[1960 + k + 1];
    bhn0 = b_hh[3920 + k];  bhn1 = b_hh[3920 + k + 1];
  }
  __syncthreads();

  for (int t = 0; t < 32; ++t) {
    // ---- stage h (batched tagged poll for t>=1); gi for t=0 only ----
    if (t == 0) {
      for (int i = tid; i < 7840; i += 512) {
        int b = i / 1960, k = i - b * 1960;
        s_h[b * 1984 + k] = f2bf(hx0[i]);
      }
      if (tid < 96) {
        int gg = tid >> 5, bb = (tid >> 3) & 3, kk = tid & 7;
        s_gi[0][tid] = gi[(size_t)(bb * 32) * 5880 + gg * 1960 + k0 + kk];
      }
    } else {
      const unsigned long long* hin = (t & 1) ? hb1 : hb0;
      unsigned pend = 0;
#pragma unroll
      for (int r = 0; r < 8; ++r)
        if (tid + (r << 9) < 3920) pend |= (1u << r);
      while (pend) {
        unsigned long long v[8];
#pragma unroll
        for (int r = 0; r < 8; ++r)
          if (pend & (1u << r))
            v[r] = __hip_atomic_load(&hin[tid + (r << 9)], __ATOMIC_RELAXED,
                                     __HIP_MEMORY_SCOPE_AGENT);
#pragma unroll
        for (int r = 0; r < 8; ++r) {
          if ((pend & (1u << r)) && (unsigned)(v[r] >> 32) >= (unsigned)t) {
            int i = tid + (r << 9);
            int b = i / 980, kp = i - b * 980;
            reinterpret_cast<unsigned int*>(s_h)[b * 992 + kp] = (unsigned)v[r];
            pend &= ~(1u << r);
          }
        }
        if (pend) __builtin_amdgcn_s_sleep(0);
      }
    }
    __syncthreads();  // barrier A: stage complete

    // ---- MFMA dot (waves 0-3); wave 4 prefetches gi for step t+1 ----
    if (wv < 4) {
      f32x4 acc0 = (f32x4){0.f, 0.f, 0.f, 0.f};
      f32x4 acc1 = (f32x4){0.f, 0.f, 0.f, 0.f};
      for (int kc = wv; kc < 62; kc += 4) {
        short8v bfr = *reinterpret_cast<const short8v*>(&s_h[(li & 3) * 1984 + kc * 32 + g2 * 8]);
        short8v a0 = *reinterpret_cast<const short8v*>(&s_w[((size_t)kc * 64 + lane) * 8]);
        short8v a1 = *reinterpret_cast<const short8v*>(&s_w[((size_t)(62 + kc) * 64 + lane) * 8]);
        acc0 = __builtin_amdgcn_mfma_f32_16x16x32_bf16(a0, bfr, acc0, 0, 0, 0);
        acc1 = __builtin_amdgcn_mfma_f32_16x16x32_bf16(a1, bfr, acc1, 0, 0, 0);
      }
      *reinterpret_cast<f32x4*>(&s_part[((wv * 2 + 0) * 64 + lane) * 4]) = acc0;
      *reinterpret_cast<f32x4*>(&s_part[((wv * 2 + 1) * 64 + lane) * 4]) = acc1;
    } else if (wv == 4 && t + 1 < 32) {
      int q = tid - 256;  // 0..63 (use first 96 slots across waves 4-5? keep to 64: split below)
      if (q < 96) {       // wave4 has 64 lanes; handle 64 here...
        int gg = q >> 5, bb = (q >> 3) & 3, kk = q & 7;
        s_gi[(t + 1) & 1][q] = gi[(size_t)(bb * 32 + t + 1) * 5880 + gg * 1960 + k0 + kk];
      }
    } else if (wv == 5 && t + 1 < 32) {
      int q = 64 + (tid - 320);  // 64..95 from wave 5's first 32 lanes
      if (q < 96) {
        int gg = q >> 5, bb = (q >> 3) & 3, kk = q & 7;
        s_gi[(t + 1) & 1][q] = gi[(size_t)(bb * 32 + t + 1) * 5880 + gg * 1960 + k0 + kk];
      }
    }
    __syncthreads();  // barrier B: s_part ready

    // ---- update (16 threads) + publish tagged ----
    unsigned long long* hout = (t & 1) ? hb0 : hb1;
    if (tid < 16) {
      const int cb = tid >> 2, p = tid & 3;
      const int kk = 2 * p;
      auto psum = [&](int mt, int m) -> float {
        int base = mt * 256 + ((m >> 2) * 16 + cb) * 4 + (m & 3);
        return ((s_part[base] + s_part[base + 512]) +
                (s_part[base + 1024] + s_part[base + 1536]));
      };
      float ghr0 = psum(0, kk),     ghr1 = psum(0, kk + 1);
      float ghz0 = psum(0, 8 + kk), ghz1 = psum(0, 8 + kk + 1);
      float ghn0 = psum(1, kk),     ghn1 = psum(1, kk + 1);
      float r0 = sigmf(s_gi[t & 1][cb * 8 + kk] + ghr0 + bhr0);
      float z0 = sigmf(s_gi[t & 1][32 + cb * 8 + kk] + ghz0 + bhz0);
      float n0 = tanhfast(s_gi[t & 1][64 + cb * 8 + kk] + r0 * (ghn0 + bhn0));
      float h0v = (1.f - z0) * n0 + z0 * hp0;
      float r1 = sigmf(s_gi[t & 1][cb * 8 + kk + 1] + ghr1 + bhr1);
      float z1 = sigmf(s_gi[t & 1][32 + cb * 8 + kk + 1] + ghz1 + bhz1);
      float n1 = tanhfast(s_gi[t & 1][64 + cb * 8 + kk + 1] + r1 * (ghn1 + bhn1));
      float h1v = (1.f - z1) * n1 + z1 * hp1;
      hp0 = h0v; hp1 = h1v;
      unsigned long long packed =
          ((unsigned long long)(unsigned)(t + 1) << 32) |
          (unsigned long long)((unsigned)f2bf(h0v) | ((unsigned)f2bf(h1v) << 16));
      __hip_atomic_store(&hout[cb * 980 + (k0 >> 1) + p], packed,
                         __ATOMIC_RELAXED, __HIP_MEMORY_SCOPE_AGENT);
    }
    __syncthreads();  // barrier C: keep non-update waves from racing into next poll
  }

  // ---- fused fc + softmax (block 0 only) ----
  if (bid == 0) {
    unsigned pend = 0;
#pragma unroll
    for (int r = 0; r < 8; ++r)
      if (tid + (r << 9) < 3920) pend |= (1u << r);
    while (pend) {
      unsigned long long v[8];
#pragma unroll
      for (int r = 0; r < 8; ++r)
        if (pend & (1u << r))
          v[r] = __hip_atomic_load(&hb0[tid + (r << 9)], __ATOMIC_RELAXED,
                                   __HIP_MEMORY_SCOPE_AGENT);
#pragma unroll
      for (int r = 0; r < 8; ++r) {
        if ((pend & (1u << r)) && (unsigned)(v[r] >> 32) >= 32u) {
          int i = tid + (r << 9);
          int b = i / 980, kp = i - b * 980;
          reinterpret_cast<unsigned int*>(s_h)[b * 992 + kp] = (unsigned)v[r];
          pend &= ~(1u << r);
        }
      }
      if (pend) __builtin_amdgcn_s_sleep(0);
    }
    __syncthreads();
    if (tid < 64) {
      const int l = tid;
      float acc[8];
#pragma unroll
      for (int i = 0; i < 8; ++i) acc[i] = 0.f;
      for (int k = l; k < 1960; k += 64) {
        const float w0 = fc_w[k], w1 = fc_w[1960 + k];
#pragma unroll
        for (int b = 0; b < 4; ++b) {
          const float hv = bf2f(s_h[b * 1984 + k]);
          acc[b * 2 + 0] += hv * w0;
          acc[b * 2 + 1] += hv * w1;
        }
      }
#pragma unroll
      for (int i = 0; i < 8; ++i) {
        float a = acc[i];
#pragma unroll
        for (int off = 32; off; off >>= 1) a += __shfl_xor(a, off, 64);
        acc[i] = a;
      }
      if (l == 0) {
#pragma unroll
        for (int b = 0; b < 4; ++b) {
          const float l0 = acc[b * 2] + fc_b[0], l1 = acc[b * 2 + 1] + fc_b[1];
          const float m = fmaxf(l0, l1);
          const float e0 = __expf(l0 - m), e1 = __expf(l1 - m);
          const float s = e0 + e1;
          out[b * 2 + 0] = e0 / s;
          out[b * 2 + 1] = e1 / s;
        }
        for (int i = 0; i < 4; ++i) out[8 + i] = (float)labels[i];
      }
    }
  }
}

extern "C" void kernel_launch(void* const* d_in, const int* in_sizes, int n_in,
                              void* d_out, int out_size, void* d_ws, size_t ws_size,
                              hipStream_t stream) {
  const float* x       = (const float*)d_in[0];
  const float* hx0     = (const float*)d_in[1];
  const int*   labels  = (const int*)d_in[2];
  const float* conv1_w = (const float*)d_in[3];
  const float* conv1_b = (const float*)d_in[4];
  const float* conv2_w = (const float*)d_in[5];
  const float* conv2_b = (const float*)d_in[6];
  const float* w_ih    = (const float*)d_in[7];
  const float* w_hh    = (const float*)d_in[8];
  const float* b_ih    = (const float*)d_in[9];
  const float* b_hh    = (const float*)d_in[10];
  const float* fc_w    = (const float*)d_in[11];
  const float* fc_b    = (const float*)d_in[12];

  char* ws = (char*)d_ws;
  size_t off = 0;
  unsigned short* pool1 = (unsigned short*)(ws + off); off += (size_t)128 * 84 * 41 * 64 * 2;  // 56.4MB
  unsigned short* feat_bf = (unsigned short*)(ws + off); off += (size_t)128 * KP * 2;          // 0.5MB
  float* gi    = (float*)(ws + off); off += (size_t)128 * 5880 * 4;                            // 3.0MB
  unsigned short* whh_bf = (unsigned short*)(ws + off); off += (size_t)5880 * 1960 * 2;        // 23.0MB
  unsigned long long* hb0 = (unsigned long long*)(ws + off); off += (size_t)4 * 980 * 8;       // 31.4KB
  unsigned long long* hb1 = (unsigned long long*)(ws + off); off += (size_t)4 * 980 * 8;       // 31.4KB
  unsigned short* w1f = (unsigned short*)(ws + off); off += (size_t)4 * 3 * 64 * 8 * 2;        // 12KB
  unsigned short* w2f = (unsigned short*)(ws + off); off += (size_t)32 * 64 * 8 * 2;           // 32KB

  k_prep<<<2137, 256, 0, stream>>>(w_hh, whh_bf, conv1_w, conv1_b, w1f,
                                   conv2_w, w2f, feat_bf, hb0, hb1);

  dim3 g1(128, 21);
  k_conv1<<<g1, 256, 0, stream>>>(x, w1f, pool1);

  dim3 g2(128, 14);
  k_conv2<<<g2, 128, 0, stream>>>(pool1, w2f, conv2_b, feat_bf);

  dim3 g3(368, 2);
  k_gi<<<g3, 256, 0, stream>>>(feat_bf, w_ih, b_ih, gi);

  // all 32 GRU steps + fused fc; final h_32 in hb0; out written by block 0
  void* gru_args[] = {(void*)&whh_bf, (void*)&b_hh, (void*)&gi, (void*)&hx0,
                      (void*)&hb0, (void*)&hb1, (void*)&fc_w, (void*)&fc_b,
                      (void*)&labels, (void*)&d_out};
  hipLaunchCooperativeKernel((const void*)k_gru, dim3(GRU_BLOCKS), dim3(512), gru_args, 0, stream);
}

// Round 21
// 363.938 us; speedup vs baseline: 1.1508x; 1.0264x over previous
//
#include <hip/hip_runtime.h>
#include <hip/hip_cooperative_groups.h>

// ---------- helpers ----------
__device__ __forceinline__ float bf2f(unsigned short u) {
  union { unsigned int i; float f; } v; v.i = ((unsigned int)u) << 16; return v.f;
}
__device__ __forceinline__ unsigned short f2bf(float f) {
  union { float f; unsigned int i; } v; v.f = f;
  unsigned int x = v.i;
  return (unsigned short)((x + 0x7fffu + ((x >> 16) & 1u)) >> 16);
}
__device__ __forceinline__ float sigmf(float x) { return 1.f / (1.f + __expf(-x)); }
__device__ __forceinline__ float tanhfast(float x) {
  float xc = fminf(fmaxf(x, -15.f), 15.f);
  float e = __expf(2.f * xc);
  return (e - 1.f) / (e + 1.f);
}

typedef float f32x4 __attribute__((ext_vector_type(4)));
typedef short short8v __attribute__((ext_vector_type(8)));
typedef short short4v __attribute__((ext_vector_type(4)));

// pack 8 f32 -> 8 bf16 (truncate)
__device__ __forceinline__ short8v pack8(const float* p) {
  union { short8v s; unsigned int u[4]; } r;
#pragma unroll
  for (int i = 0; i < 4; ++i) {
    unsigned int lo = __float_as_uint(p[2 * i]) >> 16;
    unsigned int hi = __float_as_uint(p[2 * i + 1]) & 0xFFFF0000u;
    r.u[i] = hi | lo;
  }
  return r.s;
}

#define KP 1984
#define GRU_BLOCKS 245
#define C1_PLANE 2860
#define C1_BLOCKS 2688   // 128 * 21
#define CVT_BLOCKS 2048

// ---------- small prep: w1frag [0,24) | w2frag [24,88) | featpad [88] ----------
__global__ void k_prep(const float* __restrict__ w1, const float* __restrict__ b1,
                       unsigned short* __restrict__ w1f,
                       const float* __restrict__ w2, unsigned short* __restrict__ w2f,
                       unsigned short* __restrict__ feat_bf,
                       unsigned long long* __restrict__ hb0,
                       unsigned long long* __restrict__ hb1) {
  const int b = blockIdx.x;
  const int tid = threadIdx.x;
  if (b < 24) {
    int idx = b * 256 + tid;
    if (idx < 4 * 3 * 64 * 8) {
      int j = idx & 7, l = (idx >> 3) & 63;
      int rest = idx >> 9;
      int s = rest % 3, ocf = rest / 3;
      int oc = ocf * 16 + (l & 15);
      int k = s * 32 + (l >> 4) * 8 + j;
      float v = 0.f;
      if (k < 64)       v = w1[oc * 81 + (k >> 3) * 9 + (k & 7)];
      else if (k < 72)  v = w1[oc * 81 + 72 + (k - 64)];
      else if (k < 80)  v = w1[oc * 81 + (k - 72) * 9 + 8];
      else if (k == 80) v = w1[oc * 81 + 80];
      else if (k == 81) v = b1[oc];
      w1f[idx] = f2bf(v);
    }
  } else if (b < 88) {
    int idx = (b - 24) * 256 + tid;
    if (idx < 32 * 64 * 8) {
      int j = idx & 7, l = (idx >> 3) & 63, s = idx >> 9;
      int oc = l & 15;
      int k = s * 32 + (l >> 4) * 8 + j;
      int t = k >> 6, ch = k & 63, fr = t >> 2, fc = t & 3;
      float v = (oc < 5) ? w2[((oc * 64 + ch) * 4 + fr) * 4 + fc] : 0.f;
      w2f[idx] = f2bf(v);
    }
  } else {
    for (int i = tid; i < 128 * 24; i += 256) {
      int n = i / 24, k = 1960 + i % 24;
      feat_bf[(size_t)n * KP + k] = 0;
    }
    for (int i = tid; i < 3920; i += 256) {
      hb0[i] = 0ull;
      hb1[i] = 0ull;
    }
  }
}

// ---------- kernel 1: conv1 MFMA (blocks [0,2688)) + w_hh cvt overlap (blocks [2688,4736)) ----------
__global__ __launch_bounds__(256) void k_conv1(const float* __restrict__ x,
                                               const unsigned short* __restrict__ w1f,
                                               unsigned short* __restrict__ pool1,
                                               const float* __restrict__ w_hh,
                                               unsigned short* __restrict__ whh_bf) {
  const int blk = blockIdx.x;
  const int tid = threadIdx.x;
  if (blk >= C1_BLOCKS) {
    // w_hh f32 -> bf16 (memory-bound; overlaps with conv1's MFMA blocks)
    const int n4 = 5880 * 1960 / 4;
    for (int i = (blk - C1_BLOCKS) * 256 + tid; i < n4; i += CVT_BLOCKS * 256) {
      float4 v = *reinterpret_cast<const float4*>(&w_hh[i * 4]);
      ushort4 u;
      u.x = f2bf(v.x); u.y = f2bf(v.y); u.z = f2bf(v.z); u.w = f2bf(v.w);
      *reinterpret_cast<ushort4*>(&whh_bf[i * 4]) = u;
    }
    return;
  }
  const int n = blk & 127, qrg = blk >> 7;
  const int b = n >> 5, w = n & 31;
  __shared__ __align__(16) unsigned short s_b[4 * C1_PLANE];  // 22880 B
  for (int i = tid; i < 20 * 132; i += 256) {
    int lr = i / 132, lc = i % 132;
    int f = 12 * qrg + lr - 2;
    int t = lc - 2;
    float v = 0.f;
    if (f >= 0 && f < 257 && t >= 0 && t < 128)
      v = x[((size_t)b * 258 + 1 + f) * 2176 + w * 64 + t];
    unsigned short bf = f2bf(v);
#pragma unroll
    for (int m = 0; m < 4; ++m) s_b[m * C1_PLANE + lr * 140 + lc + m] = bf;
  }
  const int lane = tid & 63, wv = tid >> 6;
  short8v bw[4][3];
#pragma unroll
  for (int ocf = 0; ocf < 4; ++ocf)
#pragma unroll
    for (int s = 0; s < 3; ++s)
      bw[ocf][s] = *reinterpret_cast<const short8v*>(&w1f[(((ocf * 3) + s) * 64 + lane) * 8]);
  __syncthreads();

  const int qr = qrg * 4 + wv;
  const int li = lane & 15, g = lane >> 4;

  for (int pgt = 0; pgt < 3; ++pgt) {
    int pg = pgt * 16 + li;
    if (pg > 40) pg = 40;
    f32x4 pm[4];
#pragma unroll
    for (int ocf = 0; ocf < 4; ++ocf) pm[ocf] = (f32x4){-3.4e38f, -3.4e38f, -3.4e38f, -3.4e38f};

    for (int rr = 0; rr < 3; ++rr) {
      const int lrb = 3 * wv + rr;
#pragma unroll
      for (int phi = 0; phi < 3; ++phi) {
        const int c = 3 * pg + phi;
        const int m = (-c) & 3;
        const unsigned short* hb = &s_b[m * C1_PLANE + c + m];
        f32x4 acc[4];
#pragma unroll
        for (int ocf = 0; ocf < 4; ++ocf) acc[ocf] = (f32x4){0.f, 0.f, 0.f, 0.f};
        const unsigned short* p0 = hb + (lrb + g) * 140;
        short8v a0 = __builtin_shufflevector(*reinterpret_cast<const short4v*>(p0),
                                             *reinterpret_cast<const short4v*>(p0 + 4),
                                             0, 1, 2, 3, 4, 5, 6, 7);
#pragma unroll
        for (int ocf = 0; ocf < 4; ++ocf)
          acc[ocf] = __builtin_amdgcn_mfma_f32_16x16x32_bf16(a0, bw[ocf][0], acc[ocf], 0, 0, 0);
        const unsigned short* p1 = p0 + 4 * 140;
        short8v a1 = __builtin_shufflevector(*reinterpret_cast<const short4v*>(p1),
                                             *reinterpret_cast<const short4v*>(p1 + 4),
                                             0, 1, 2, 3, 4, 5, 6, 7);
#pragma unroll
        for (int ocf = 0; ocf < 4; ++ocf)
          acc[ocf] = __builtin_amdgcn_mfma_f32_16x16x32_bf16(a1, bw[ocf][1], acc[ocf], 0, 0, 0);
        short8v a2;
        if (g == 0) {
          const unsigned short* p2 = p0 + 8 * 140;
          a2 = __builtin_shufflevector(*reinterpret_cast<const short4v*>(p2),
                                       *reinterpret_cast<const short4v*>(p2 + 4),
                                       0, 1, 2, 3, 4, 5, 6, 7);
        } else if (g == 1) {
          const unsigned short* pv = &s_b[lrb * 140 + c + 8];
          union { short8v s8; unsigned int u[4]; } r;
          r.u[0] = (unsigned)pv[0]       | ((unsigned)pv[140] << 16);
          r.u[1] = (unsigned)pv[2 * 140] | ((unsigned)pv[3 * 140] << 16);
          r.u[2] = (unsigned)pv[4 * 140] | ((unsigned)pv[5 * 140] << 16);
          r.u[3] = (unsigned)pv[6 * 140] | ((unsigned)pv[7 * 140] << 16);
          a2 = r.s8;
        } else if (g == 2) {
          union { short8v s8; unsigned int u[4]; } r;
          r.u[0] = (unsigned)s_b[(lrb + 8) * 140 + c + 8] | 0x3F800000u;  // corner | bf16(1.0)<<16
          r.u[1] = 0; r.u[2] = 0; r.u[3] = 0;
          a2 = r.s8;
        } else {
          a2 = (short8v){0, 0, 0, 0, 0, 0, 0, 0};
        }
#pragma unroll
        for (int ocf = 0; ocf < 4; ++ocf)
          acc[ocf] = __builtin_amdgcn_mfma_f32_16x16x32_bf16(a2, bw[ocf][2], acc[ocf], 0, 0, 0);
#pragma unroll
        for (int ocf = 0; ocf < 4; ++ocf) {
#pragma unroll
          for (int i = 0; i < 4; ++i) pm[ocf][i] = fmaxf(pm[ocf][i], acc[ocf][i]);
        }
      }
    }
#pragma unroll
    for (int ocf = 0; ocf < 4; ++ocf) {
#pragma unroll
      for (int i = 0; i < 4; ++i) {
        int pg2 = pgt * 16 + g * 4 + i;
        if (pg2 <= 40) {
          int oc = ocf * 16 + li;
          pool1[(((size_t)n * 84 + qr) * 41 + pg2) * 64 + oc] = f2bf(sigmf(pm[ocf][i]));
        }
      }
    }
  }
}

// ---------- kernel 2: conv2 MFMA, LDS-staged A, weights in regs ----------
__global__ __launch_bounds__(128, 2) void k_conv2(const unsigned short* __restrict__ pool1,
                                                  const unsigned short* __restrict__ w2f,
                                                  const float* __restrict__ b2,
                                                  unsigned short* __restrict__ feat_bf) {
  const int n = blockIdx.x, qg = blockIdx.y;
  __shared__ __align__(16) unsigned short s_a[9 * 46 * 64];
  const int tid = threadIdx.x;
  const int lane = tid & 63, wv = tid >> 6;
  short8v bwr[32];
#pragma unroll
  for (int s = 0; s < 32; ++s)
    bwr[s] = *reinterpret_cast<const short8v*>(&w2f[(s * 64 + lane) * 8]);
  const int r0 = 6 * qg - 2;
  for (int idx = tid; idx < 9 * 46 * 8; idx += 128) {
    int row = idx / (46 * 8);
    int rem = idx - row * (46 * 8);
    int lc = rem >> 3, cp = rem & 7;
    int gr = r0 + row, gc = lc - 2;
    short8v v = {0, 0, 0, 0, 0, 0, 0, 0};
    if ((unsigned)gr < 84u && (unsigned)gc < 41u)
      v = *reinterpret_cast<const short8v*>(&pool1[(((size_t)n * 84 + gr) * 41 + gc) * 64 + cp * 8]);
    int rot = (cp * 8 + lc * 8) & 63;
    *reinterpret_cast<short8v*>(&s_a[(row * 46 + lc) * 64 + rot]) = v;
  }
  __syncthreads();

  const int q = qg * 2 + wv;
  const int li = lane & 15, g = lane >> 4;
  const int pg = li > 13 ? 13 : li;
  f32x4 pm = (f32x4){-3.4e38f, -3.4e38f, -3.4e38f, -3.4e38f};

  for (int rr = 0; rr < 3; ++rr) {
#pragma unroll
    for (int phi = 0; phi < 3; ++phi) {
      f32x4 acc[4];
#pragma unroll
      for (int i = 0; i < 4; ++i) acc[i] = (f32x4){0.f, 0.f, 0.f, 0.f};
#pragma unroll
      for (int s = 0; s < 32; ++s) {
        const int t = s >> 1, h = s & 1;
        const int fr = t >> 2, fc = t & 3;
        const int srow = 3 * wv + rr + fr;
        const int lc = 3 * pg + phi + fc;
        const int rot = (h * 32 + g * 8 + lc * 8) & 63;
        short8v a = *reinterpret_cast<const short8v*>(&s_a[(srow * 46 + lc) * 64 + rot]);
        acc[s & 3] = __builtin_amdgcn_mfma_f32_16x16x32_bf16(a, bwr[s], acc[s & 3], 0, 0, 0);
      }
      f32x4 sum;
#pragma unroll
      for (int i = 0; i < 4; ++i) sum[i] = (acc[0][i] + acc[1][i]) + (acc[2][i] + acc[3][i]);
#pragma unroll
      for (int i = 0; i < 4; ++i) pm[i] = fmaxf(pm[i], sum[i]);
    }
  }
  if (li < 5) {
#pragma unroll
    for (int i = 0; i < 4; ++i) {
      int pq = g * 4 + i;
      if (pq < 14)
        feat_bf[(size_t)n * KP + li * 392 + q * 14 + pq] = f2bf(sigmf(pm[i] + b2[li]));
    }
  }
}

// ---------- kernel 4: gi MFMA GEMM (reads w_ih f32 directly, inline bf16 pack) ----------
__global__ __launch_bounds__(256) void k_gi(const unsigned short* __restrict__ feat_bf,
                                            const float* __restrict__ w_ih,
                                            const float* __restrict__ b_ih,
                                            float* __restrict__ gi) {
  const int bx = blockIdx.x, bm = blockIdx.y;
  const int w = threadIdx.x >> 6, lane = threadIdx.x & 63;
  const int li = lane & 15, g = lane >> 4;
  const int j = bx * 16 + li;
  const int jc = j < 5880 ? j : 5879;
  const unsigned short* ap = feat_bf + (size_t)(bm * 64 + w * 16 + li) * KP + g * 8;
  const float* bp = w_ih + (size_t)jc * 1960 + g * 8;
  const short8v z8 = {0, 0, 0, 0, 0, 0, 0, 0};
  f32x4 acc0 = (f32x4){0.f, 0.f, 0.f, 0.f};
  f32x4 acc1 = (f32x4){0.f, 0.f, 0.f, 0.f};
  for (int kc = 0; kc < 62; kc += 2) {
    short8v a0 = *reinterpret_cast<const short8v*>(ap + kc * 32);
    short8v a1 = *reinterpret_cast<const short8v*>(ap + kc * 32 + 32);
    short8v b0 = pack8(bp + kc * 32);
    short8v b1 = (kc != 60 || g == 0) ? pack8(bp + kc * 32 + 32) : z8;
    acc0 = __builtin_amdgcn_mfma_f32_16x16x32_bf16(a0, b0, acc0, 0, 0, 0);
    acc1 = __builtin_amdgcn_mfma_f32_16x16x32_bf16(a1, b1, acc1, 0, 0, 0);
  }
  if (j < 5880) {
    const float bi = b_ih[j];
    const int n0 = bm * 64 + w * 16 + g * 4;
#pragma unroll
    for (int i = 0; i < 4; ++i)
      gi[(size_t)(n0 + i) * 5880 + j] = acc0[i] + acc1[i] + bi;
  }
}

// ---------- kernel 5: persistent GRU (bf16 preload, gi prefetch under dot, fused fc) ----------
__global__ __launch_bounds__(512) void k_gru(const unsigned short* __restrict__ whh,
                                             const float* __restrict__ b_hh,
                                             const float* __restrict__ gi,
                                             const float* __restrict__ hx0,
                                             unsigned long long* __restrict__ hb0,
                                             unsigned long long* __restrict__ hb1,
                                             const float* __restrict__ fc_w,
                                             const float* __restrict__ fc_b,
                                             const int* __restrict__ labels,
                                             float* __restrict__ out) {
  __shared__ __align__(16) unsigned short s_w[2 * 62 * 64 * 8];  // 126976 B
  __shared__ __align__(16) unsigned short s_h[4 * 1984];         // 15872 B
  __shared__ float s_part[4 * 2 * 64 * 4];                        // 8192 B
  __shared__ float s_gi[2][96];
  const int tid = threadIdx.x;
  const int bid = blockIdx.x;
  const int k0 = bid * 8;
  const int lane = tid & 63, wv = tid >> 6;
  const int li = lane & 15, g2 = lane >> 4;

  // preload w A-fragments from bf16 global (consecutive threads -> consecutive LDS 16B)
  for (int idx = tid; idx < 2 * 62 * 64; idx += 512) {
    int mt = idx / 3968;
    int rem = idx - mt * 3968;
    int kc = rem >> 6, l = rem & 63;
    int lli = l & 15, lg2 = l >> 4;
    int k = kc * 32 + lg2 * 8;
    short8v v = {0, 0, 0, 0, 0, 0, 0, 0};
    bool rowok = (mt == 0) ? true : (lli < 8);
    if (rowok && k < 1960) {
      int g = (mt == 0) ? (lli >> 3) : 2;
      int kk = (mt == 0) ? (lli & 7) : lli;
      v = *reinterpret_cast<const short8v*>(&whh[(size_t)(g * 1960 + k0 + kk) * 1960 + k]);
    }
    *reinterpret_cast<short8v*>(&s_w[(size_t)idx * 8]) = v;
  }
  for (int i = tid; i < 4 * 992; i += 512) reinterpret_cast<unsigned int*>(s_h)[i] = 0u;

  float hp0 = 0.f, hp1 = 0.f, bhr0 = 0, bhr1 = 0, bhz0 = 0, bhz1 = 0, bhn0 = 0, bhn1 = 0;
  if (tid < 16) {
    int cb = tid >> 2, p = tid & 3;
    int k = k0 + 2 * p;
    hp0 = hx0[cb * 1960 + k];
    hp1 = hx0[cb * 1960 + k + 1];
    bhr0 = b_hh[k];         bhr1 = b_hh[k + 1];
    bhz0 = b_hh[1960 + k];  bhz1 = b_hh[1960 + k + 1];
    bhn0 = b_hh[3920 + k];  bhn1 = b_hh[3920 + k + 1];
  }
  __syncthreads();

  for (int t = 0; t < 32; ++t) {
    // ---- stage h (batched tagged poll for t>=1); gi for t=0 only ----
    if (t == 0) {
      for (int i = tid; i < 7840; i += 512) {
        int b = i / 1960, k = i - b * 1960;
        s_h[b * 1984 + k] = f2bf(hx0[i]);
      }
      if (tid < 96) {
        int gg = tid >> 5, bb = (tid >> 3) & 3, kk = tid & 7;
        s_gi[0][tid] = gi[(size_t)(bb * 32) * 5880 + gg * 1960 + k0 + kk];
      }
    } else {
      const unsigned long long* hin = (t & 1) ? hb1 : hb0;
      unsigned pend = 0;
#pragma unroll
      for (int r = 0; r < 8; ++r)
        if (tid + (r << 9) < 3920) pend |= (1u << r);
      while (pend) {
        unsigned long long v[8];
#pragma unroll
        for (int r = 0; r < 8; ++r)
          if (pend & (1u << r))
            v[r] = __hip_atomic_load(&hin[tid + (r << 9)], __ATOMIC_RELAXED,
                                     __HIP_MEMORY_SCOPE_AGENT);
#pragma unroll
        for (int r = 0; r < 8; ++r) {
          if ((pend & (1u << r)) && (unsigned)(v[r] >> 32) >= (unsigned)t) {
            int i = tid + (r << 9);
            int b = i / 980, kp = i - b * 980;
            reinterpret_cast<unsigned int*>(s_h)[b * 992 + kp] = (unsigned)v[r];
            pend &= ~(1u << r);
          }
        }
        if (pend) __builtin_amdgcn_s_sleep(0);
      }
    }
    __syncthreads();  // barrier A: stage complete

    // ---- MFMA dot (waves 0-3); waves 4-5 prefetch gi for step t+1 ----
    if (wv < 4) {
      f32x4 acc0 = (f32x4){0.f, 0.f, 0.f, 0.f};
      f32x4 acc1 = (f32x4){0.f, 0.f, 0.f, 0.f};
      for (int kc = wv; kc < 62; kc += 4) {
        short8v bfr = *reinterpret_cast<const short8v*>(&s_h[(li & 3) * 1984 + kc * 32 + g2 * 8]);
        short8v a0 = *reinterpret_cast<const short8v*>(&s_w[((size_t)kc * 64 + lane) * 8]);
        short8v a1 = *reinterpret_cast<const short8v*>(&s_w[((size_t)(62 + kc) * 64 + lane) * 8]);
        acc0 = __builtin_amdgcn_mfma_f32_16x16x32_bf16(a0, bfr, acc0, 0, 0, 0);
        acc1 = __builtin_amdgcn_mfma_f32_16x16x32_bf16(a1, bfr, acc1, 0, 0, 0);
      }
      *reinterpret_cast<f32x4*>(&s_part[((wv * 2 + 0) * 64 + lane) * 4]) = acc0;
      *reinterpret_cast<f32x4*>(&s_part[((wv * 2 + 1) * 64 + lane) * 4]) = acc1;
    } else if (wv == 4 && t + 1 < 32) {
      int q = tid - 256;  // 0..63
      if (q < 96) {
        int gg = q >> 5, bb = (q >> 3) & 3, kk = q & 7;
        s_gi[(t + 1) & 1][q] = gi[(size_t)(bb * 32 + t + 1) * 5880 + gg * 1960 + k0 + kk];
      }
    } else if (wv == 5 && t + 1 < 32) {
      int q = 64 + (tid - 320);  // 64..95 from wave 5's first 32 lanes
      if (q < 96) {
        int gg = q >> 5, bb = (q >> 3) & 3, kk = q & 7;
        s_gi[(t + 1) & 1][q] = gi[(size_t)(bb * 32 + t + 1) * 5880 + gg * 1960 + k0 + kk];
      }
    }
    __syncthreads();  // barrier B: s_part ready

    // ---- update (16 threads) + publish tagged ----
    unsigned long long* hout = (t & 1) ? hb0 : hb1;
    if (tid < 16) {
      const int cb = tid >> 2, p = tid & 3;
      const int kk = 2 * p;
      auto psum = [&](int mt, int m) -> float {
        int base = mt * 256 + ((m >> 2) * 16 + cb) * 4 + (m & 3);
        return ((s_part[base] + s_part[base + 512]) +
                (s_part[base + 1024] + s_part[base + 1536]));
      };
      float ghr0 = psum(0, kk),     ghr1 = psum(0, kk + 1);
      float ghz0 = psum(0, 8 + kk), ghz1 = psum(0, 8 + kk + 1);
      float ghn0 = psum(1, kk),     ghn1 = psum(1, kk + 1);
      float r0 = sigmf(s_gi[t & 1][cb * 8 + kk] + ghr0 + bhr0);
      float z0 = sigmf(s_gi[t & 1][32 + cb * 8 + kk] + ghz0 + bhz0);
      float n0 = tanhfast(s_gi[t & 1][64 + cb * 8 + kk] + r0 * (ghn0 + bhn0));
      float h0v = (1.f - z0) * n0 + z0 * hp0;
      float r1 = sigmf(s_gi[t & 1][cb * 8 + kk + 1] + ghr1 + bhr1);
      float z1 = sigmf(s_gi[t & 1][32 + cb * 8 + kk + 1] + ghz1 + bhz1);
      float n1 = tanhfast(s_gi[t & 1][64 + cb * 8 + kk + 1] + r1 * (ghn1 + bhn1));
      float h1v = (1.f - z1) * n1 + z1 * hp1;
      hp0 = h0v; hp1 = h1v;
      unsigned long long packed =
          ((unsigned long long)(unsigned)(t + 1) << 32) |
          (unsigned long long)((unsigned)f2bf(h0v) | ((unsigned)f2bf(h1v) << 16));
      __hip_atomic_store(&hout[cb * 980 + (k0 >> 1) + p], packed,
                         __ATOMIC_RELAXED, __HIP_MEMORY_SCOPE_AGENT);
    }
    __syncthreads();  // barrier C: keep non-update waves from racing into next poll
  }

  // ---- fused fc + softmax (block 0 only) ----
  if (bid == 0) {
    unsigned pend = 0;
#pragma unroll
    for (int r = 0; r < 8; ++r)
      if (tid + (r << 9) < 3920) pend |= (1u << r);
    while (pend) {
      unsigned long long v[8];
#pragma unroll
      for (int r = 0; r < 8; ++r)
        if (pend & (1u << r))
          v[r] = __hip_atomic_load(&hb0[tid + (r << 9)], __ATOMIC_RELAXED,
                                   __HIP_MEMORY_SCOPE_AGENT);
#pragma unroll
      for (int r = 0; r < 8; ++r) {
        if ((pend & (1u << r)) && (unsigned)(v[r] >> 32) >= 32u) {
          int i = tid + (r << 9);
          int b = i / 980, kp = i - b * 980;
          reinterpret_cast<unsigned int*>(s_h)[b * 992 + kp] = (unsigned)v[r];
          pend &= ~(1u << r);
        }
      }
      if (pend) __builtin_amdgcn_s_sleep(0);
    }
    __syncthreads();
    if (tid < 64) {
      const int l = tid;
      float acc[8];
#pragma unroll
      for (int i = 0; i < 8; ++i) acc[i] = 0.f;
      for (int k = l; k < 1960; k += 64) {
        const float w0 = fc_w[k], w1 = fc_w[1960 + k];
#pragma unroll
        for (int b = 0; b < 4; ++b) {
          const float hv = bf2f(s_h[b * 1984 + k]);
          acc[b * 2 + 0] += hv * w0;
          acc[b * 2 + 1] += hv * w1;
        }
      }
#pragma unroll
      for (int i = 0; i < 8; ++i) {
        float a = acc[i];
#pragma unroll
        for (int off = 32; off; off >>= 1) a += __shfl_xor(a, off, 64);
        acc[i] = a;
      }
      if (l == 0) {
#pragma unroll
        for (int b = 0; b < 4; ++b) {
          const float l0 = acc[b * 2] + fc_b[0], l1 = acc[b * 2 + 1] + fc_b[1];
          const float m = fmaxf(l0, l1);
          const float e0 = __expf(l0 - m), e1 = __expf(l1 - m);
          const float s = e0 + e1;
          out[b * 2 + 0] = e0 / s;
          out[b * 2 + 1] = e1 / s;
        }
        for (int i = 0; i < 4; ++i) out[8 + i] = (float)labels[i];
      }
    }
  }
}

extern "C" void kernel_launch(void* const* d_in, const int* in_sizes, int n_in,
                              void* d_out, int out_size, void* d_ws, size_t ws_size,
                              hipStream_t stream) {
  const float* x       = (const float*)d_in[0];
  const float* hx0     = (const float*)d_in[1];
  const int*   labels  = (const int*)d_in[2];
  const float* conv1_w = (const float*)d_in[3];
  const float* conv1_b = (const float*)d_in[4];
  const float* conv2_w = (const float*)d_in[5];
  const float* conv2_b = (const float*)d_in[6];
  const float* w_ih    = (const float*)d_in[7];
  const float* w_hh    = (const float*)d_in[8];
  const float* b_ih    = (const float*)d_in[9];
  const float* b_hh    = (const float*)d_in[10];
  const float* fc_w    = (const float*)d_in[11];
  const float* fc_b    = (const float*)d_in[12];

  char* ws = (char*)d_ws;
  size_t off = 0;
  unsigned short* pool1 = (unsigned short*)(ws + off); off += (size_t)128 * 84 * 41 * 64 * 2;  // 56.4MB
  unsigned short* feat_bf = (unsigned short*)(ws + off); off += (size_t)128 * KP * 2;          // 0.5MB
  float* gi    = (float*)(ws + off); off += (size_t)128 * 5880 * 4;                            // 3.0MB
  unsigned short* whh_bf = (unsigned short*)(ws + off); off += (size_t)5880 * 1960 * 2;        // 23.0MB
  unsigned long long* hb0 = (unsigned long long*)(ws + off); off += (size_t)4 * 980 * 8;       // 31.4KB
  unsigned long long* hb1 = (unsigned long long*)(ws + off); off += (size_t)4 * 980 * 8;       // 31.4KB
  unsigned short* w1f = (unsigned short*)(ws + off); off += (size_t)4 * 3 * 64 * 8 * 2;        // 12KB
  unsigned short* w2f = (unsigned short*)(ws + off); off += (size_t)32 * 64 * 8 * 2;           // 32KB

  k_prep<<<89, 256, 0, stream>>>(conv1_w, conv1_b, w1f, conv2_w, w2f, feat_bf, hb0, hb1);

  // conv1 (2688 blocks) + w_hh cvt (2048 blocks) fused: memory-bound cvt hides under MFMA
  k_conv1<<<C1_BLOCKS + CVT_BLOCKS, 256, 0, stream>>>(x, w1f, pool1, w_hh, whh_bf);

  dim3 g2(128, 14);
  k_conv2<<<g2, 128, 0, stream>>>(pool1, w2f, conv2_b, feat_bf);

  dim3 g3(368, 2);
  k_gi<<<g3, 256, 0, stream>>>(feat_bf, w_ih, b_ih, gi);

  // all 32 GRU steps + fused fc; final h_32 in hb0; out written by block 0
  void* gru_args[] = {(void*)&whh_bf, (void*)&b_hh, (void*)&gi, (void*)&hx0,
                      (void*)&hb0, (void*)&hb1, (void*)&fc_w, (void*)&fc_b,
                      (void*)&labels, (void*)&d_out};
  hipLaunchCooperativeKernel((const void*)k_gru, dim3(GRU_BLOCKS), dim3(512), gru_args, 0, stream);
}